// Round 20
// baseline (883.959 us; speedup 1.0000x reference)
//
#include <hip/hip_runtime.h>
#include <cmath>

#define TPB 256
#define TPB2 512

// ---- problem constants ----
constexpr int Bb = 32, Cc = 256, Ff = 1024, Oo = 201;
constexpr int H0 = 10, S0 = 8,  N0 = Bb * S0 * S0;   // 2048
constexpr int H1 = 20, S1 = 18, N1 = Bb * S1 * S1;   // 10368
constexpr int NT_ALL = N0 + N1;                      // 12416
constexpr int KC = Cc * 9;                           // 2304
constexpr int KP = Cc * 16;                          // 4096 (tap-padded conv1 K)
constexpr int L5 = S0 * S0, L4 = S1 * S1, LT = L5 + L4;  // 64, 324, 388
constexpr int CHMAX = 4224;                          // chunks: 4096,4096,4224
constexpr int M1 = Bb * H0 * H0;                     // 3200 (conv1 scale boundary)
constexpr int MCONV = M1 + Bb * H1 * H1;             // 16000

// ---- element counts ----
constexpr size_t SZ_CW  = (size_t)Ff * KC;      // 2,359,296
constexpr size_t SZ_W0P = (size_t)Cc * KP;      // 1,048,576
constexpr size_t SZ_LWP = (size_t)256 * Ff;     // 262,144 (padded to 256 rows)

// ---- workspace byte offsets ----
constexpr size_t B_CWH = 0;
constexpr size_t B_CWL = B_CWH + SZ_CW * 2;
constexpr size_t B_GXY = B_CWL + SZ_CW * 2;
constexpr size_t B_LWH = B_GXY + (size_t)NT_ALL * 18 * 4;
constexpr size_t B_LWL = B_LWH + SZ_LWP * 2;
constexpr size_t B_SC  = B_LWL + SZ_LWP * 2;
constexpr size_t B_XSH = B_SC + (size_t)Bb * Oo * LT * 4;
constexpr size_t B_XSL = B_XSH + (size_t)CHMAX * KC * 2;
constexpr size_t B_FCH = B_XSL + (size_t)CHMAX * KC * 2;
constexpr size_t B_FCL = B_FCH + (size_t)CHMAX * Ff * 2;
constexpr size_t B_RP  = B_FCL + (size_t)CHMAX * Ff * 2;   // ~77.6 MB
constexpr size_t B_END = B_RP + 256;
// aliases (disjoint lifetimes)
constexpr size_t B_W0H = B_XSH;
constexpr size_t B_W0L = B_XSH + SZ_W0P * 2;
constexpr size_t B_H0  = B_XSL;
constexpr size_t B_H1  = B_XSL + (size_t)Bb * Cc * H0 * H0 * 4;
constexpr size_t B_C2  = B_FCH;

// ---- output layout (floats) ----
constexpr size_t O_LIK = 0;
constexpr size_t O_BOX = O_LIK + Bb * Oo;
constexpr size_t O_NT  = O_BOX + Bb * 5;
constexpr size_t O_TD  = O_NT + Bb * 5;
constexpr size_t O_REG = O_TD + (size_t)NT_ALL * 6;

typedef __attribute__((ext_vector_type(8))) short bf16x8;
typedef __attribute__((ext_vector_type(4))) float f32x4;

__device__ __forceinline__ void tsplit(float v, short& h, short& l) {
    unsigned u = __builtin_bit_cast(unsigned, v);
    h = (short)(u >> 16);
    float hf = __builtin_bit_cast(float, u & 0xffff0000u);
    float r = v - hf;                       // exact
    l = (short)(__builtin_bit_cast(unsigned, r) >> 16);
}
__device__ __forceinline__ float clampf(float x, float lo, float hi) {
    return fminf(fmaxf(x, lo), hi);
}
__device__ __forceinline__ void gload16(const void* g, void* l) {
    __builtin_amdgcn_global_load_lds(
        (const __attribute__((address_space(1))) void*)g,
        (__attribute__((address_space(3))) void*)l, 16, 0, 0);
}
// fragment-swizzled element index: panel 128 rows x step 32 k -> 4096 block
__device__ __forceinline__ size_t aidx(int row, int k, int KD) {
    return ((size_t)(row >> 7) * (KD >> 5) + (k >> 5)) * 4096
         + (size_t)(((row & 127) >> 4) * 512 + ((k >> 3) & 3) * 128 + (row & 15) * 8 + (k & 7));
}

// ===================== weight split kernels =====================
// cw: k' = t*256 + c, frag-swizzled; thread = (row, tap, 8-ch group)
__global__ __launch_bounds__(TPB)
void splitp_k(const float* __restrict__ src, short* __restrict__ hi,
              short* __restrict__ lo, int nrows)
{
    int idx = blockIdx.x * TPB + threadIdx.x;
    if (idx >= nrows * 288) return;
    int row = idx / 288, r = idx - row * 288;
    int t = r >> 5, cg = r & 31;
    const float* sp = src + (size_t)row * KC + (size_t)cg * 8 * 9 + t;
    bf16x8 hv, lv;
    #pragma unroll
    for (int e = 0; e < 8; e++) {
        short h, l; tsplit(sp[e * 9], h, l);
        hv[e] = h; lv[e] = l;
    }
    size_t dst = aidx(row, t * 256 + cg * 8, KC);
    *(bf16x8*)&hi[dst] = hv;
    *(bf16x8*)&lo[dst] = lv;
}

__global__ __launch_bounds__(TPB)
void splitp16_k(const float* __restrict__ src, short* __restrict__ hi,
                short* __restrict__ lo, int nrows) // w0: k' = c*16 + t (conv1, row-major)
{
    int idx = blockIdx.x * TPB + threadIdx.x;
    if (idx >= nrows * KP) return;
    int row = idx >> 12, kq = idx & (KP - 1);
    int c = kq >> 4, t = kq & 15;
    float v = (t < 9) ? src[(size_t)row * KC + c * 9 + t] : 0.f;
    short h, l; tsplit(v, h, l);
    hi[idx] = h; lo[idx] = l;
}

__global__ __launch_bounds__(TPB)
void splitlw_k(const float* __restrict__ src, short* __restrict__ hi,
               short* __restrict__ lo)             // lw, 256-row pad, frag-swizzled
{
    int idx = blockIdx.x * TPB + threadIdx.x;
    if (idx >= (int)SZ_LWP) return;
    int row = idx >> 10, k = idx & 1023;
    float v = (row < Oo) ? src[idx] : 0.f;
    short h, l; tsplit(v, h, l);
    size_t dst = aidx(row, k, Ff);
    hi[dst] = h; lo[dst] = l;
}

// ===================== mat_k: materialize sampled im2col chunk (frag-swizzled) ====
__global__ __launch_bounds__(TPB)
void mat_k(const float* __restrict__ x0, const float* __restrict__ x1,
           const float* __restrict__ gxy, short* __restrict__ xsH,
           short* __restrict__ xsL, int base, int rows)
{
    int idx = blockIdx.x * TPB + threadIdx.x;
    if (idx >= rows * 288) return;
    int mloc = idx / 288, r = idx - mloc * 288;
    int j = r >> 5, cg = r & 31;
    int m = base + mloc;
    const float* xp; int H, loc, SS;
    if (m < N0) { xp = x0; H = H0; loc = m; SS = 64; }
    else        { xp = x1; H = H1; loc = m - N0; SS = 324; }
    int b = loc / SS;
    float gx = gxy[(size_t)m * 18 + j];
    float gy = gxy[(size_t)m * 18 + 9 + j];
    float xf = floorf(gx), yf = floorf(gy);
    float wx = gx - xf, wy = gy - yf;
    int ix = (int)xf, iy = (int)yf;
    int cx0 = min(max(ix, 0), H - 1), cy0 = min(max(iy, 0), H - 1);
    bool vx0 = (ix >= 0 && ix < H), vx1 = (ix >= -1 && ix < H - 1);
    bool vy0 = (iy >= 0 && iy < H), vy1 = (iy >= -1 && iy < H - 1);
    float wxL = vx0 ? (1.f - wx) : (vx1 ? wx : 0.f);
    float wxR = (vx0 && vx1) ? wx : 0.f;
    float wyT = vy0 ? (1.f - wy) : (vy1 ? wy : 0.f);
    float wyB = (vy0 && vy1) ? wy : 0.f;
    float wTL = wyT * wxL, wTR = wyT * wxR, wBL = wyB * wxL, wBR = wyB * wxR;
    int o   = cy0 * H + cx0;
    int oTR = (wTR != 0.f) ? o + 1     : o;
    int oBL = (wBL != 0.f) ? o + H     : o;
    int oBR = (wBR != 0.f) ? o + H + 1 : o;
    const float* cp = xp + ((size_t)b * Cc + cg * 8) * (H * H);
    bf16x8 hv, lv;
    #pragma unroll
    for (int e = 0; e < 8; e++) {
        float v = cp[o] * wTL + cp[oTR] * wTR + cp[oBL] * wBL + cp[oBR] * wBR;
        short h, l; tsplit(v, h, l); hv[e] = h; lv[e] = l;
        cp += H * H;
    }
    size_t dst = aidx(mloc, j * 256 + cg * 8, KC);   // e-contiguous
    *(bf16x8*)&xsH[dst] = hv;
    *(bf16x8*)&xsL[dst] = lv;
}

// =====================================================================
// mgemm (conv1) — ROUND-19 EXACT: 128x64 tile, 512 threads, BK=64.
// =====================================================================
template<int KD>
__global__ __launch_bounds__(TPB2, 4)
void mgemm(const float* __restrict__ x0s, const float* __restrict__ x1s,
           const short* __restrict__ Bh, const short* __restrict__ Bl,
           const float* __restrict__ bias,
           float* __restrict__ outF, float* __restrict__ outF2)
{
    __shared__ short As[2][8][128][8];   // 32 KB
    __shared__ short Bs[2][8][64][8];    // 16 KB
    __shared__ float slab[3200];         // 12.8 KB

    const int tid = threadIdx.x;          // 0..511
    const int lane = tid & 63;
    const int wid = tid >> 6;             // 0..7
    const int wm = (wid >> 2) * 64, wn = (wid & 3) * 16;
    const int ml = tid & 127;
    const int sl0 = tid >> 7;             // 0..3: channel within BK=64 phase
    const int bm = blockIdx.y * 128, bn = blockIdx.x * 64;

    f32x4 acc[4];
    #pragma unroll
    for (int i = 0; i < 4; i++) acc[i] = (f32x4){0.f, 0.f, 0.f, 0.f};

    const float* xsrc = nullptr;
    int Hh = 0, PLSZr = 0, UPPr = 0, bat0 = 0, batidx = 0, nu = 0;
    float wvt[9]; int offt[9];
    {
        int lbase;
        if (bm < M1) { xsrc = x0s; Hh = H0; lbase = bm; }
        else         { xsrc = x1s; Hh = H1; lbase = bm - M1; }
        PLSZr = Hh * Hh; UPPr = PLSZr >> 2;
        int mGl = lbase + ml;
        int bA = mGl / PLSZr; int rem = mGl - bA * PLSZr;
        int yA = rem / Hh, xA = rem - (rem / Hh) * Hh;
        bat0 = lbase / PLSZr;
        int nb = (lbase + 127) / PLSZr - bat0 + 1;
        batidx = bA - bat0;
        nu = nb * 4 * UPPr;               // <= 800 float4 units
        #pragma unroll
        for (int t = 0; t < 9; t++) {
            int ky = t / 3 - 1, kx = t - (t / 3) * 3 - 1;
            int yy = yA + ky, xx = xA + kx;
            bool ok = (yy >= 0 && yy < Hh && xx >= 0 && xx < Hh);
            offt[t] = ok ? (yy * Hh + xx) : 0;
            wvt[t] = ok ? 1.f : 0.f;
        }
    }

    float4 rv0 = {}, rv1 = {};
    float4 pv0 = {}, pv1 = {};
    auto issue_loads = [&](int kb, float4& a0, float4& a1) {
        const int c0 = kb >> 4;
        #pragma unroll
        for (int q = 0; q < 2; q++) {
            int i = tid + q * TPB2;
            if (i < nu) {
                int pl = i / UPPr, u = i - pl * UPPr;
                int bi = pl >> 2, ccq = pl & 3;
                float4 v = *(const float4*)(xsrc +
                    ((size_t)(bat0 + bi) * Cc + c0 + ccq) * PLSZr + u * 4);
                if (q == 0) a0 = v; else a1 = v;
            }
        }
    };
    auto write_slab = [&](const float4& a0, const float4& a1) {
        #pragma unroll
        for (int q = 0; q < 2; q++) {
            int i = tid + q * TPB2;
            if (i < nu)
                *(float4*)&slab[i * 4] = (q == 0) ? a0 : a1;
        }
    };

    issue_loads(0, rv0, rv1);

    for (int kb = 0; kb < KD; kb += 64) {
        write_slab(rv0, rv1);
        if (kb + 64 < KD) issue_loads(kb + 64, pv0, pv1);
        __syncthreads();                           // slab visible
        {
            int hilo = wid & 1, s0 = wid >> 1;
            const short* gB = (hilo ? Bl : Bh) + (size_t)(bn + lane) * KD + kb;
            gload16(gB + s0 * 8,       &Bs[hilo][s0][0][0]);
            gload16(gB + (s0 + 4) * 8, &Bs[hilo][s0 + 4][0][0]);
        }
        {
            const float* sp = &slab[(batidx * 4 + sl0) * PLSZr];
            bf16x8 hv, lv;
            #pragma unroll
            for (int e = 0; e < 8; e++) {
                float v = sp[offt[e]] * wvt[e];
                short h, l; tsplit(v, h, l); hv[e] = h; lv[e] = l;
            }
            *(bf16x8*)&As[0][sl0 * 2][ml][0] = hv;
            *(bf16x8*)&As[1][sl0 * 2][ml][0] = lv;
            bf16x8 hv2 = {}, lv2 = {};
            { float v = sp[offt[8]] * wvt[8];
              short h, l; tsplit(v, h, l); hv2[0] = h; lv2[0] = l; }
            *(bf16x8*)&As[0][sl0 * 2 + 1][ml][0] = hv2;
            *(bf16x8*)&As[1][sl0 * 2 + 1][ml][0] = lv2;
        }
        __syncthreads();                           // As/Bs visible
        {
            const int kq = lane >> 4, r = lane & 15;
            #pragma unroll
            for (int kh = 0; kh < 2; kh++) {
                const int kgf = kh * 4 + kq;
                bf16x8 ah[4], al[4];
                #pragma unroll
                for (int i = 0; i < 4; i++) {
                    ah[i] = *(const bf16x8*)&As[0][kgf][wm + i * 16 + r][0];
                    al[i] = *(const bf16x8*)&As[1][kgf][wm + i * 16 + r][0];
                }
                bf16x8 bh = *(const bf16x8*)&Bs[0][kgf][wn + r][0];
                bf16x8 bl = *(const bf16x8*)&Bs[1][kgf][wn + r][0];
                #pragma unroll
                for (int i = 0; i < 4; i++) {
                    acc[i] = __builtin_amdgcn_mfma_f32_16x16x32_bf16(ah[i], bh, acc[i], 0, 0, 0);
                    acc[i] = __builtin_amdgcn_mfma_f32_16x16x32_bf16(al[i], bh, acc[i], 0, 0, 0);
                    acc[i] = __builtin_amdgcn_mfma_f32_16x16x32_bf16(ah[i], bl, acc[i], 0, 0, 0);
                }
            }
        }
        rv0 = pv0; rv1 = pv1;
    }

    const int kq = lane >> 4, rr = lane & 15;
    #pragma unroll
    for (int i = 0; i < 4; i++) {
        #pragma unroll
        for (int r = 0; r < 4; r++) {
            const int gm = bm + wm + i * 16 + kq * 4 + r;
            const int gn = bn + wn + rr;
            float v = acc[i][r];
            float* hp; int Hq, lr;
            if (gm < M1) { hp = outF; Hq = H0; lr = gm; }
            else         { hp = outF2; Hq = H1; lr = gm - M1; }
            int PL = Hq * Hq;
            int bq = lr / PL; int rem = lr - bq * PL;
            int yq = rem / Hq; int xq = rem - yq * Hq;
            hp[((size_t)bq * Cc + gn) * PL + yq * Hq + xq] = fmaxf(v + bias[gn], 0.f);
        }
    }
}

// =====================================================================
// mgemm5 (feat MODE 4): BNT=128, SINGLE register buffer (acc 64 + A 32
// + B 32 ~= 143 VGPR -> lb3 holds, 12 waves/CU). A-traffic HALVED vs
// BNT=64 (8 n-blocks instead of 16). NO LDS, NO BARRIERS.
// GRID: dim3(8, mt) -- n fastest.
// =====================================================================
template<int KD>
__global__ __launch_bounds__(TPB, 3)
void mgemm5(const short* __restrict__ AsH_, const short* __restrict__ AsL_,
            const short* __restrict__ Bh, const short* __restrict__ Bl,
            const float* __restrict__ bias,
            short* __restrict__ outH, short* __restrict__ outL)
{
    constexpr int NSTEP = KD / 32;          // 72
    const int tid = threadIdx.x;
    const int lane = tid & 63;
    const int wid = tid >> 6;
    const int wm = (wid >> 1) * 64, wn = (wid & 1) * 64;
    const int bm = blockIdx.y * 128, bn = blockIdx.x * 128;  // n fastest

    const size_t ablk0 = (size_t)(bm >> 7) * NSTEP * 4096;
    const size_t bblk0 = (size_t)(bn >> 7) * NSTEP * 4096;
    const int ai = wm >> 4;                  // 0 or 4
    const int bi = wn >> 4;                  // 0 or 4
    const int lo8 = lane * 8;

    f32x4 acc[4][4];
    #pragma unroll
    for (int i = 0; i < 4; i++)
        #pragma unroll
        for (int j = 0; j < 4; j++)
            acc[i][j] = (f32x4){0.f, 0.f, 0.f, 0.f};

    bf16x8 Ah[4], Al[4], Bhf[4], Blf[4];

    for (int t = 0; t < NSTEP; ++t) {
        const size_t ab = ablk0 + (size_t)t * 4096;
        const size_t bb = bblk0 + (size_t)t * 4096;
        #pragma unroll
        for (int i = 0; i < 4; i++) {
            Ah[i] = *(const bf16x8*)(AsH_ + ab + (ai + i) * 512 + lo8);
            Al[i] = *(const bf16x8*)(AsL_ + ab + (ai + i) * 512 + lo8);
        }
        #pragma unroll
        for (int j = 0; j < 4; j++) {
            Bhf[j] = *(const bf16x8*)(Bh + bb + (bi + j) * 512 + lo8);
            Blf[j] = *(const bf16x8*)(Bl + bb + (bi + j) * 512 + lo8);
        }
        #pragma unroll
        for (int i = 0; i < 4; i++)
            #pragma unroll
            for (int j = 0; j < 4; j++) {
                acc[i][j] = __builtin_amdgcn_mfma_f32_16x16x32_bf16(Ah[i], Bhf[j], acc[i][j], 0, 0, 0);
                acc[i][j] = __builtin_amdgcn_mfma_f32_16x16x32_bf16(Al[i], Bhf[j], acc[i][j], 0, 0, 0);
                acc[i][j] = __builtin_amdgcn_mfma_f32_16x16x32_bf16(Ah[i], Blf[j], acc[i][j], 0, 0, 0);
            }
    }

    const int kq = lane >> 4, rr = lane & 15;
    #pragma unroll
    for (int i = 0; i < 4; i++) {
        #pragma unroll
        for (int r = 0; r < 4; r++) {
            const int gm = bm + wm + i * 16 + kq * 4 + r;
            #pragma unroll
            for (int j = 0; j < 4; j++) {
                const int gn = bn + wn + j * 16 + rr;
                float q = fmaxf(acc[i][j][r] + bias[gn], 0.f);
                short h, l; tsplit(q, h, l);
                size_t d = aidx(gm, gn, Ff);    // swizzled for scores-A
                outH[d] = h;
                outL[d] = l;
            }
        }
    }
}

// =====================================================================
// mgemm4 (scores MODE 5) — ROUND-15/19 EXACT: NO LDS, NO BARRIERS,
// BN=64, lb3, reg ping-pong. GRID: dim3(4, mt).
// =====================================================================
template<int KD>
__global__ __launch_bounds__(TPB, 3)
void mgemm4(const short* __restrict__ AsH_, const short* __restrict__ AsL_,
            const short* __restrict__ Bh, const short* __restrict__ Bl,
            const float* __restrict__ bias,
            float* __restrict__ outF, int base)
{
    constexpr int NSTEP = KD / 32;          // 32
    const int tid = threadIdx.x;
    const int lane = tid & 63;
    const int wid = tid >> 6;
    const int wm = (wid >> 1) * 64, wn = (wid & 1) * 32;
    const int bm = blockIdx.y * 128, bn = blockIdx.x * 64;   // n fastest

    const size_t ablk0 = (size_t)(bm >> 7) * NSTEP * 4096;
    const size_t bblk0 = (size_t)(bn >> 7) * NSTEP * 4096;
    const int ai = wm >> 4;
    const int bi = ((bn & 64) + wn) >> 4;
    const int lo8 = lane * 8;

    f32x4 acc[4][2];
    #pragma unroll
    for (int i = 0; i < 4; i++)
        #pragma unroll
        for (int j = 0; j < 2; j++)
            acc[i][j] = (f32x4){0.f, 0.f, 0.f, 0.f};

    bf16x8 Ah[2][4], Al[2][4], Bhf[2][2], Blf[2][2];

    auto LOAD = [&](int s, int t) {
        const size_t ab = ablk0 + (size_t)t * 4096;
        const size_t bb = bblk0 + (size_t)t * 4096;
        #pragma unroll
        for (int i = 0; i < 4; i++) {
            Ah[s][i] = *(const bf16x8*)(AsH_ + ab + (ai + i) * 512 + lo8);
            Al[s][i] = *(const bf16x8*)(AsL_ + ab + (ai + i) * 512 + lo8);
        }
        #pragma unroll
        for (int j = 0; j < 2; j++) {
            Bhf[s][j] = *(const bf16x8*)(Bh + bb + (bi + j) * 512 + lo8);
            Blf[s][j] = *(const bf16x8*)(Bl + bb + (bi + j) * 512 + lo8);
        }
    };
    auto MM = [&](int s) {
        #pragma unroll
        for (int i = 0; i < 4; i++)
            #pragma unroll
            for (int j = 0; j < 2; j++) {
                acc[i][j] = __builtin_amdgcn_mfma_f32_16x16x32_bf16(Ah[s][i], Bhf[s][j], acc[i][j], 0, 0, 0);
                acc[i][j] = __builtin_amdgcn_mfma_f32_16x16x32_bf16(Al[s][i], Bhf[s][j], acc[i][j], 0, 0, 0);
                acc[i][j] = __builtin_amdgcn_mfma_f32_16x16x32_bf16(Ah[s][i], Blf[s][j], acc[i][j], 0, 0, 0);
            }
    };

    LOAD(0, 0);
    for (int t = 0; t < NSTEP; t += 2) {
        LOAD(1, t + 1);
        MM(0);
        if (t + 2 < NSTEP) LOAD(0, t + 2);
        MM(1);
    }

    const int kq = lane >> 4, rr = lane & 15;
    #pragma unroll
    for (int i = 0; i < 4; i++) {
        #pragma unroll
        for (int r = 0; r < 4; r++) {
            const int gm = bm + wm + i * 16 + kq * 4 + r;
            #pragma unroll
            for (int j = 0; j < 2; j++) {
                const int gn = bn + wn + j * 16 + rr;
                if (gn < Oo) {
                    int g = base + gm;
                    int bq, pos;
                    if (g < N0) {
                        int lo = g & 63; bq = g >> 6;
                        pos = (lo & 7) * 8 + (lo >> 3);
                    } else {
                        int gg = g - N0; bq = gg / 324; int lo = gg - bq * 324;
                        int xq = lo / 18, yq = lo - xq * 18;
                        pos = L5 + yq * 18 + xq;
                    }
                    outF[((size_t)bq * Oo + gn) * LT + pos] = acc[i][j][r] + bias[gn];
                }
            }
        }
    }
}

// ===================== conv2 =====================
__global__ __launch_bounds__(TPB)
void conv2_k(const float* __restrict__ h0, const float* __restrict__ h1,
             const float* __restrict__ w1, float* __restrict__ c2)
{
    __shared__ float wl[6][KC];
    __shared__ float part[8][32][6];
    const int tid = threadIdx.x;
    for (int i = tid; i < 6 * KC; i += TPB) wl[i / KC][i - (i / KC) * KC] = w1[i];
    __syncthreads();
    const int row = blockIdx.x * 32 + (tid & 31);
    const int cig = tid >> 5;
    const float* hsrc; int H, S, loc;
    if (row < N0) { hsrc = h0; H = H0; S = S0; loc = row; }
    else          { hsrc = h1; H = H1; S = S1; loc = row - N0; }
    int SS = S * S;
    int b = loc / SS; int rem = loc - b * SS;
    int xq = rem / S; int yq = rem - xq * S;
    float acc[6] = {};
    for (int ci = cig * 32; ci < cig * 32 + 32; ci++) {
        const float* hp = hsrc + ((size_t)(b * Cc + ci) * H + yq) * H + xq;
        #pragma unroll
        for (int ky = 0; ky < 3; ky++)
            #pragma unroll
            for (int kx = 0; kx < 3; kx++) {
                float a = hp[ky * H + kx];
                int kk = ci * 9 + ky * 3 + kx;
                #pragma unroll
                for (int n = 0; n < 6; n++) acc[n] = fmaf(a, wl[n][kk], acc[n]);
            }
    }
    #pragma unroll
    for (int n = 0; n < 6; n++) part[cig][tid & 31][n] = acc[n];
    __syncthreads();
    if (cig == 0) {
        #pragma unroll
        for (int n = 0; n < 6; n++) {
            float s = 0.f;
            for (int g = 0; g < 8; g++) s += part[g][tid & 31][n];
            c2[(size_t)row * 6 + n] = s;
        }
    }
}

// ===================== theta / aux =====================
__global__ __launch_bounds__(TPB)
void theta_aux_k(const float* __restrict__ c2, const int* __restrict__ checkp,
                 float* __restrict__ td, float* __restrict__ gxy)
{
    int n = blockIdx.x * TPB + threadIdx.x;
    if (n >= NT_ALL) return;
    float omc = 1.0f - (float)checkp[0];
    const float I[6] = {1.f, 0.f, 0.f, 0.f, 1.f, 0.f};
    float th[6];
    #pragma unroll
    for (int i = 0; i < 6; i++) {
        float v = c2[(size_t)n * 6 + i] * omc + I[i];
        th[i] = v;
        td[(size_t)n * 6 + i] = I[i] - v;
    }
    int S, loc;
    if (n < N0) { S = S0; loc = n; } else { S = S1; loc = n - N0; }
    int SS = S * S;
    int rem = loc % SS;
    int xx = rem / S, yy = rem % S;
    #pragma unroll
    for (int ky = 0; ky < 3; ky++)
        #pragma unroll
        for (int kx = 0; kx < 3; kx++) {
            float bx = (float)(kx - 1), by = (float)(ky - 1);
            gxy[(size_t)n * 18 + ky * 3 + kx]     = th[0] * bx + th[1] * by + th[2] + 1.0f + (float)xx;
            gxy[(size_t)n * 18 + 9 + ky * 3 + kx] = th[3] * bx + th[4] * by + th[5] + 1.0f + (float)yy;
        }
}

// ==== fused softmax stats + likelihood + boxes (one kernel per batch) ====
__global__ __launch_bounds__(TPB)
void statsbox_k(const float* __restrict__ sc, const float* __restrict__ gxy,
                const int* __restrict__ imdp, float* __restrict__ lik,
                float* __restrict__ boxes, float* __restrict__ boxesNT,
                float* __restrict__ regpart)
{
    int b = blockIdx.x, tid = threadIdx.x;
    const float* p = sc + (size_t)b * Oo * LT;
    constexpr int PER = Oo * LT;
    __shared__ float red[TPB];
    __shared__ int redi[TPB];

    float m = -3.4e38f;
    for (int i = tid; i < PER; i += TPB) m = fmaxf(m, p[i]);
    red[tid] = m;
    for (int off = 128; off; off >>= 1) { __syncthreads(); if (tid < off) red[tid] = fmaxf(red[tid], red[tid + off]); }
    __syncthreads();
    m = red[0];
    __syncthreads();

    float so = 0.f;
    if (tid < Oo) {
        const float* q = p + (size_t)tid * LT;
        for (int i = 0; i < LT; i++) so += expf(q[i] - m);
    }
    red[tid] = so;
    for (int off = 128; off; off >>= 1) { __syncthreads(); if (tid < off) red[tid] += red[tid + off]; }
    __syncthreads();
    float smt = red[0];
    float mylik = (tid < Oo) ? so / smt : -3.4e38f;
    if (tid < Oo) lik[b * Oo + tid] = mylik;
    __syncthreads();

    red[tid] = mylik; redi[tid] = tid;
    for (int off = 128; off; off >>= 1) {
        __syncthreads();
        if (tid < off) {
            float v2 = red[tid + off]; int i2 = redi[tid + off];
            if (v2 > red[tid] || (v2 == red[tid] && i2 < redi[tid])) { red[tid] = v2; redi[tid] = i2; }
        }
    }
    __syncthreads();
    int pred = redi[0];
    __syncthreads();

    const float* pr = p + (size_t)pred * LT;
    float b5 = -3.4e38f; int i5 = 1 << 30;
    float b4 = -3.4e38f; int i4 = 1 << 30;
    for (int pos = tid; pos < LT; pos += TPB) {
        float s = pr[pos];
        if (pos < L5) { if (s > b5) { b5 = s; i5 = pos; } }
        else { int q = pos - L5; if (s > b4) { b4 = s; i4 = q; } }
    }
    red[tid] = b5; redi[tid] = i5;
    for (int off = 128; off; off >>= 1) {
        __syncthreads();
        if (tid < off) {
            float v2 = red[tid + off]; int i2 = redi[tid + off];
            if (v2 > red[tid] || (v2 == red[tid] && i2 < redi[tid])) { red[tid] = v2; redi[tid] = i2; }
        }
    }
    __syncthreads();
    float m5 = red[0]; int d5 = redi[0];
    __syncthreads();
    red[tid] = b4; redi[tid] = i4;
    for (int off = 128; off; off >>= 1) {
        __syncthreads();
        if (tid < off) {
            float v2 = red[tid + off]; int i2 = redi[tid + off];
            if (v2 > red[tid] || (v2 == red[tid] && i2 < redi[tid])) { red[tid] = v2; redi[tid] = i2; }
        }
    }
    __syncthreads();
    float m4 = red[0]; int d4 = redi[0];

    if (tid == 0) {
        float conf5 = expf(m5 - m) / smt;
        float conf4 = expf(m4 - m) / smt;
        float imd = (float)imdp[0];
        float lo = 0.f, hi = imd - 1.f;

        int xx5 = d5 % S0, yy5 = d5 / S0;
        int n5 = b * (S0 * S0) + xx5 * S0 + yy5;
        const float* g = gxy + (size_t)n5 * 18;
        float txm = 1e30f, txM = -1e30f, tym = 1e30f, tyM = -1e30f;
        for (int j = 0; j < 9; j++) {
            float tx = g[j] / 9.f, ty = g[9 + j] / 9.f;
            txm = fminf(txm, tx); txM = fmaxf(txM, tx);
            tym = fminf(tym, ty); tyM = fmaxf(tyM, ty);
        }
        float box5[5] = { clampf(txm * imd, lo, hi), clampf(tym * imd, lo, hi),
                          clampf(txM * imd, lo, hi), clampf(tyM * imd, lo, hi), conf5 };
        float nt5[5]  = { clampf((float)xx5 / 9.f * imd, lo, hi), clampf((float)yy5 / 9.f * imd, lo, hi),
                          clampf((float)(xx5 + 2) / 9.f * imd, lo, hi), clampf((float)(yy5 + 2) / 9.f * imd, lo, hi), conf5 };

        int xx4 = d4 % S1, yy4 = d4 / S1;
        int n4 = N0 + b * (S1 * S1) + xx4 * S1 + yy4;
        const float* g4 = gxy + (size_t)n4 * 18;
        float txm4 = 1e30f, txM4 = -1e30f, tym4 = 1e30f, tyM4 = -1e30f;
        for (int j = 0; j < 9; j++) {
            float tx = g4[j] / 19.f, ty = g4[9 + j] / 19.f;
            txm4 = fminf(txm4, tx); txM4 = fmaxf(txM4, tx);
            tym4 = fminf(tym4, ty); tyM4 = fmaxf(tyM4, ty);
        }
        float box4[5] = { clampf(txm4 * imd, lo, hi), clampf(tym4 * imd, lo, hi),
                          clampf(txM4 * imd, lo, hi), clampf(tyM4 * imd, lo, hi), conf4 };
        float nt4[5]  = { clampf((float)xx4 / 19.f * imd, lo, hi), clampf((float)yy4 / 19.f * imd, lo, hi),
                          clampf((float)(xx4 + 2) / 19.f * imd, lo, hi), clampf((float)(yy4 + 2) / 19.f * imd, lo, hi), conf4 };

        int mi = (conf4 > conf5) ? 1 : 0;
        for (int i = 0; i < 5; i++) {
            boxes[b * 5 + i]   = mi ? box4[i] : box5[i];
            boxesNT[b * 5 + i] = mi ? nt4[i] : nt5[i];
        }
        regpart[b] = fmaxf(conf4 - conf5, 0.f);
    }
}

__global__ void reg_k(const float* __restrict__ regpart, float* __restrict__ outreg)
{
    if (threadIdx.x == 0) {
        float s = 0.f;
        for (int b = 0; b < Bb; b++) s += regpart[b];
        outreg[0] = s;
    }
}

__global__ void sentinel_k(float* out, int n)
{
    int i = blockIdx.x * 256 + threadIdx.x;
    if (i < n) out[i] = 12345.0f;
}

extern "C" void kernel_launch(void* const* d_in, const int* in_sizes, int n_in,
                              void* d_out, int out_size, void* d_ws, size_t ws_size,
                              hipStream_t stream)
{
    const float* x0 = (const float*)d_in[0];
    const float* x1 = (const float*)d_in[1];
    const float* w0 = (const float*)d_in[2];
    const float* b0 = (const float*)d_in[3];
    const float* w1 = (const float*)d_in[4];
    const float* cw = (const float*)d_in[5];
    const float* cb = (const float*)d_in[6];
    const float* lw = (const float*)d_in[7];
    const float* lb = (const float*)d_in[8];
    const int* checkp = (const int*)d_in[9];
    const int* imdp   = (const int*)d_in[10];

    if (ws_size < B_END) {
        sentinel_k<<<dim3((out_size + 255) / 256), dim3(256), 0, stream>>>((float*)d_out, out_size);
        return;
    }

    char* wsb = (char*)d_ws;
    short* cwh = (short*)(wsb + B_CWH);
    short* cwl = (short*)(wsb + B_CWL);
    float* gxy = (float*)(wsb + B_GXY);
    short* lwh = (short*)(wsb + B_LWH);
    short* lwl = (short*)(wsb + B_LWL);
    float* sc  = (float*)(wsb + B_SC);
    short* xsH = (short*)(wsb + B_XSH);
    short* xsL = (short*)(wsb + B_XSL);
    short* fcH = (short*)(wsb + B_FCH);
    short* fcL = (short*)(wsb + B_FCL);
    float* rp  = (float*)(wsb + B_RP);
    short* w0h = (short*)(wsb + B_W0H);
    short* w0l = (short*)(wsb + B_W0L);
    float* h0  = (float*)(wsb + B_H0);
    float* h1  = (float*)(wsb + B_H1);
    float* c2  = (float*)(wsb + B_C2);

    float* out   = (float*)d_out;
    float* o_lik = out + O_LIK;
    float* o_box = out + O_BOX;
    float* o_nt  = out + O_NT;
    float* o_td  = out + O_TD;
    float* o_reg = out + O_REG;

    dim3 blk(TPB);

    // weight splits (cw/lw frag-swizzled; w0 conv1 layout)
    splitp_k  <<<dim3((Ff * 288 + TPB - 1) / TPB), blk, 0, stream>>>(cw, cwh, cwl, Ff);
    splitp16_k<<<dim3((int)((SZ_W0P + TPB - 1) / TPB)), blk, 0, stream>>>(w0, w0h, w0l, Cc);
    splitlw_k <<<dim3((int)((SZ_LWP + TPB - 1) / TPB)), blk, 0, stream>>>(lw, lwh, lwl);

    // merged conv1 (+bias, relu) -> h0/h1   [128x64 tile, 512 threads, BK=64]
    mgemm<KP><<<dim3(4, MCONV / 128), dim3(TPB2), 0, stream>>>(
        x0, x1, w0h, w0l, b0, h0, h1);

    // conv2 -> c2
    conv2_k<<<dim3(NT_ALL / 32), blk, 0, stream>>>(h0, h1, w1, c2);

    // theta, theta_diff, sampling coords
    theta_aux_k<<<dim3((NT_ALL + TPB - 1) / TPB), blk, 0, stream>>>(c2, checkp, o_td, gxy);

    // chunked: materialize xs (swizzled) -> feat GEMM (BNT=128 single-buf)
    //          -> scores GEMM
    const int bases[3] = {0, 4096, 8192};
    const int sizes[3] = {4096, 4096, 4224};
    for (int c = 0; c < 3; c++) {
        int basei = bases[c], rows = sizes[c];
        int mt = rows / 128;
        mat_k<<<dim3((rows * 288 + TPB - 1) / TPB), blk, 0, stream>>>(
            x0, x1, gxy, xsH, xsL, basei, rows);
        mgemm5<KC><<<dim3(8, mt), blk, 0, stream>>>(
            xsH, xsL, cwh, cwl, cb, fcH, fcL);
        mgemm4<Ff><<<dim3(4, mt), blk, 0, stream>>>(
            fcH, fcL, lwh, lwl, lb, sc, basei);
    }

    // fused softmax stats + likelihood + boxes, then reg
    statsbox_k<<<dim3(Bb), blk, 0, stream>>>(sc, gxy, imdp, o_lik, o_box, o_nt, rp);
    reg_k<<<dim3(1), dim3(64), 0, stream>>>(rp, o_reg);
}

// Round 21
// 856.400 us; speedup vs baseline: 1.0322x; 1.0322x over previous
//
#include <hip/hip_runtime.h>
#include <cmath>

#define TPB 256
#define TPB2 512

// ---- problem constants ----
constexpr int Bb = 32, Cc = 256, Ff = 1024, Oo = 201;
constexpr int H0 = 10, S0 = 8,  N0 = Bb * S0 * S0;   // 2048
constexpr int H1 = 20, S1 = 18, N1 = Bb * S1 * S1;   // 10368
constexpr int NT_ALL = N0 + N1;                      // 12416
constexpr int KC = Cc * 9;                           // 2304
constexpr int KP = Cc * 16;                          // 4096 (tap-padded conv1 K)
constexpr int L5 = S0 * S0, L4 = S1 * S1, LT = L5 + L4;  // 64, 324, 388
constexpr int CHMAX = 4224;                          // chunks: 4096,4096,4224
constexpr int M1 = Bb * H0 * H0;                     // 3200 (conv1 scale boundary)
constexpr int MCONV = M1 + Bb * H1 * H1;             // 16000

// ---- element counts ----
constexpr size_t SZ_CW  = (size_t)Ff * KC;      // 2,359,296
constexpr size_t SZ_W0P = (size_t)Cc * KP;      // 1,048,576
constexpr size_t SZ_LWP = (size_t)256 * Ff;     // 262,144 (padded to 256 rows)

// ---- workspace byte offsets ----
constexpr size_t B_CWH = 0;
constexpr size_t B_CWL = B_CWH + SZ_CW * 2;
constexpr size_t B_GXY = B_CWL + SZ_CW * 2;
constexpr size_t B_LWH = B_GXY + (size_t)NT_ALL * 18 * 4;
constexpr size_t B_LWL = B_LWH + SZ_LWP * 2;
constexpr size_t B_SC  = B_LWL + SZ_LWP * 2;
constexpr size_t B_XSH = B_SC + (size_t)Bb * Oo * LT * 4;
constexpr size_t B_XSL = B_XSH + (size_t)CHMAX * KC * 2;
constexpr size_t B_FCH = B_XSL + (size_t)CHMAX * KC * 2;
constexpr size_t B_FCL = B_FCH + (size_t)CHMAX * Ff * 2;
constexpr size_t B_RP  = B_FCL + (size_t)CHMAX * Ff * 2;   // ~77.6 MB
constexpr size_t B_END = B_RP + 256;
// aliases (disjoint lifetimes)
constexpr size_t B_W0H = B_XSH;
constexpr size_t B_W0L = B_XSH + SZ_W0P * 2;
constexpr size_t B_H0  = B_XSL;
constexpr size_t B_H1  = B_XSL + (size_t)Bb * Cc * H0 * H0 * 4;
constexpr size_t B_C2  = B_FCH;

// ---- output layout (floats) ----
constexpr size_t O_LIK = 0;
constexpr size_t O_BOX = O_LIK + Bb * Oo;
constexpr size_t O_NT  = O_BOX + Bb * 5;
constexpr size_t O_TD  = O_NT + Bb * 5;
constexpr size_t O_REG = O_TD + (size_t)NT_ALL * 6;

typedef __attribute__((ext_vector_type(8))) short bf16x8;
typedef __attribute__((ext_vector_type(4))) float f32x4;

__device__ __forceinline__ void tsplit(float v, short& h, short& l) {
    unsigned u = __builtin_bit_cast(unsigned, v);
    h = (short)(u >> 16);
    float hf = __builtin_bit_cast(float, u & 0xffff0000u);
    float r = v - hf;                       // exact
    l = (short)(__builtin_bit_cast(unsigned, r) >> 16);
}
__device__ __forceinline__ float clampf(float x, float lo, float hi) {
    return fminf(fmaxf(x, lo), hi);
}
__device__ __forceinline__ void gload16(const void* g, void* l) {
    __builtin_amdgcn_global_load_lds(
        (const __attribute__((address_space(1))) void*)g,
        (__attribute__((address_space(3))) void*)l, 16, 0, 0);
}
// fragment-swizzled element index: panel 128 rows x step 32 k -> 4096 block
__device__ __forceinline__ size_t aidx(int row, int k, int KD) {
    return ((size_t)(row >> 7) * (KD >> 5) + (k >> 5)) * 4096
         + (size_t)(((row & 127) >> 4) * 512 + ((k >> 3) & 3) * 128 + (row & 15) * 8 + (k & 7));
}

// ===================== weight split kernels =====================
// cw: k' = t*256 + c, frag-swizzled; thread = (row, tap, 8-ch group)
__global__ __launch_bounds__(TPB)
void splitp_k(const float* __restrict__ src, short* __restrict__ hi,
              short* __restrict__ lo, int nrows)
{
    int idx = blockIdx.x * TPB + threadIdx.x;
    if (idx >= nrows * 288) return;
    int row = idx / 288, r = idx - row * 288;
    int t = r >> 5, cg = r & 31;
    const float* sp = src + (size_t)row * KC + (size_t)cg * 8 * 9 + t;
    bf16x8 hv, lv;
    #pragma unroll
    for (int e = 0; e < 8; e++) {
        short h, l; tsplit(sp[e * 9], h, l);
        hv[e] = h; lv[e] = l;
    }
    size_t dst = aidx(row, t * 256 + cg * 8, KC);
    *(bf16x8*)&hi[dst] = hv;
    *(bf16x8*)&lo[dst] = lv;
}

__global__ __launch_bounds__(TPB)
void splitp16_k(const float* __restrict__ src, short* __restrict__ hi,
                short* __restrict__ lo, int nrows) // w0: k' = c*16 + t (conv1, row-major)
{
    int idx = blockIdx.x * TPB + threadIdx.x;
    if (idx >= nrows * KP) return;
    int row = idx >> 12, kq = idx & (KP - 1);
    int c = kq >> 4, t = kq & 15;
    float v = (t < 9) ? src[(size_t)row * KC + c * 9 + t] : 0.f;
    short h, l; tsplit(v, h, l);
    hi[idx] = h; lo[idx] = l;
}

__global__ __launch_bounds__(TPB)
void splitlw_k(const float* __restrict__ src, short* __restrict__ hi,
               short* __restrict__ lo)             // lw, 256-row pad, frag-swizzled
{
    int idx = blockIdx.x * TPB + threadIdx.x;
    if (idx >= (int)SZ_LWP) return;
    int row = idx >> 10, k = idx & 1023;
    float v = (row < Oo) ? src[idx] : 0.f;
    short h, l; tsplit(v, h, l);
    size_t dst = aidx(row, k, Ff);
    hi[dst] = h; lo[dst] = l;
}

// ===================== mat_k: materialize sampled im2col chunk (frag-swizzled) ====
__global__ __launch_bounds__(TPB)
void mat_k(const float* __restrict__ x0, const float* __restrict__ x1,
           const float* __restrict__ gxy, short* __restrict__ xsH,
           short* __restrict__ xsL, int base, int rows)
{
    int idx = blockIdx.x * TPB + threadIdx.x;
    if (idx >= rows * 288) return;
    int mloc = idx / 288, r = idx - mloc * 288;
    int j = r >> 5, cg = r & 31;
    int m = base + mloc;
    const float* xp; int H, loc, SS;
    if (m < N0) { xp = x0; H = H0; loc = m; SS = 64; }
    else        { xp = x1; H = H1; loc = m - N0; SS = 324; }
    int b = loc / SS;
    float gx = gxy[(size_t)m * 18 + j];
    float gy = gxy[(size_t)m * 18 + 9 + j];
    float xf = floorf(gx), yf = floorf(gy);
    float wx = gx - xf, wy = gy - yf;
    int ix = (int)xf, iy = (int)yf;
    int cx0 = min(max(ix, 0), H - 1), cy0 = min(max(iy, 0), H - 1);
    bool vx0 = (ix >= 0 && ix < H), vx1 = (ix >= -1 && ix < H - 1);
    bool vy0 = (iy >= 0 && iy < H), vy1 = (iy >= -1 && iy < H - 1);
    float wxL = vx0 ? (1.f - wx) : (vx1 ? wx : 0.f);
    float wxR = (vx0 && vx1) ? wx : 0.f;
    float wyT = vy0 ? (1.f - wy) : (vy1 ? wy : 0.f);
    float wyB = (vy0 && vy1) ? wy : 0.f;
    float wTL = wyT * wxL, wTR = wyT * wxR, wBL = wyB * wxL, wBR = wyB * wxR;
    int o   = cy0 * H + cx0;
    int oTR = (wTR != 0.f) ? o + 1     : o;
    int oBL = (wBL != 0.f) ? o + H     : o;
    int oBR = (wBR != 0.f) ? o + H + 1 : o;
    const float* cp = xp + ((size_t)b * Cc + cg * 8) * (H * H);
    bf16x8 hv, lv;
    #pragma unroll
    for (int e = 0; e < 8; e++) {
        float v = cp[o] * wTL + cp[oTR] * wTR + cp[oBL] * wBL + cp[oBR] * wBR;
        short h, l; tsplit(v, h, l); hv[e] = h; lv[e] = l;
        cp += H * H;
    }
    size_t dst = aidx(mloc, j * 256 + cg * 8, KC);   // e-contiguous
    *(bf16x8*)&xsH[dst] = hv;
    *(bf16x8*)&xsL[dst] = lv;
}

// =====================================================================
// mgemm (conv1) — ROUND-19 EXACT: 128x64 tile, 512 threads, BK=64.
// =====================================================================
template<int KD>
__global__ __launch_bounds__(TPB2, 4)
void mgemm(const float* __restrict__ x0s, const float* __restrict__ x1s,
           const short* __restrict__ Bh, const short* __restrict__ Bl,
           const float* __restrict__ bias,
           float* __restrict__ outF, float* __restrict__ outF2)
{
    __shared__ short As[2][8][128][8];   // 32 KB
    __shared__ short Bs[2][8][64][8];    // 16 KB
    __shared__ float slab[3200];         // 12.8 KB

    const int tid = threadIdx.x;          // 0..511
    const int lane = tid & 63;
    const int wid = tid >> 6;             // 0..7
    const int wm = (wid >> 2) * 64, wn = (wid & 3) * 16;
    const int ml = tid & 127;
    const int sl0 = tid >> 7;             // 0..3: channel within BK=64 phase
    const int bm = blockIdx.y * 128, bn = blockIdx.x * 64;

    f32x4 acc[4];
    #pragma unroll
    for (int i = 0; i < 4; i++) acc[i] = (f32x4){0.f, 0.f, 0.f, 0.f};

    const float* xsrc = nullptr;
    int Hh = 0, PLSZr = 0, UPPr = 0, bat0 = 0, batidx = 0, nu = 0;
    float wvt[9]; int offt[9];
    {
        int lbase;
        if (bm < M1) { xsrc = x0s; Hh = H0; lbase = bm; }
        else         { xsrc = x1s; Hh = H1; lbase = bm - M1; }
        PLSZr = Hh * Hh; UPPr = PLSZr >> 2;
        int mGl = lbase + ml;
        int bA = mGl / PLSZr; int rem = mGl - bA * PLSZr;
        int yA = rem / Hh, xA = rem - (rem / Hh) * Hh;
        bat0 = lbase / PLSZr;
        int nb = (lbase + 127) / PLSZr - bat0 + 1;
        batidx = bA - bat0;
        nu = nb * 4 * UPPr;               // <= 800 float4 units
        #pragma unroll
        for (int t = 0; t < 9; t++) {
            int ky = t / 3 - 1, kx = t - (t / 3) * 3 - 1;
            int yy = yA + ky, xx = xA + kx;
            bool ok = (yy >= 0 && yy < Hh && xx >= 0 && xx < Hh);
            offt[t] = ok ? (yy * Hh + xx) : 0;
            wvt[t] = ok ? 1.f : 0.f;
        }
    }

    float4 rv0 = {}, rv1 = {};
    float4 pv0 = {}, pv1 = {};
    auto issue_loads = [&](int kb, float4& a0, float4& a1) {
        const int c0 = kb >> 4;
        #pragma unroll
        for (int q = 0; q < 2; q++) {
            int i = tid + q * TPB2;
            if (i < nu) {
                int pl = i / UPPr, u = i - pl * UPPr;
                int bi = pl >> 2, ccq = pl & 3;
                float4 v = *(const float4*)(xsrc +
                    ((size_t)(bat0 + bi) * Cc + c0 + ccq) * PLSZr + u * 4);
                if (q == 0) a0 = v; else a1 = v;
            }
        }
    };
    auto write_slab = [&](const float4& a0, const float4& a1) {
        #pragma unroll
        for (int q = 0; q < 2; q++) {
            int i = tid + q * TPB2;
            if (i < nu)
                *(float4*)&slab[i * 4] = (q == 0) ? a0 : a1;
        }
    };

    issue_loads(0, rv0, rv1);

    for (int kb = 0; kb < KD; kb += 64) {
        write_slab(rv0, rv1);
        if (kb + 64 < KD) issue_loads(kb + 64, pv0, pv1);
        __syncthreads();                           // slab visible
        {
            int hilo = wid & 1, s0 = wid >> 1;
            const short* gB = (hilo ? Bl : Bh) + (size_t)(bn + lane) * KD + kb;
            gload16(gB + s0 * 8,       &Bs[hilo][s0][0][0]);
            gload16(gB + (s0 + 4) * 8, &Bs[hilo][s0 + 4][0][0]);
        }
        {
            const float* sp = &slab[(batidx * 4 + sl0) * PLSZr];
            bf16x8 hv, lv;
            #pragma unroll
            for (int e = 0; e < 8; e++) {
                float v = sp[offt[e]] * wvt[e];
                short h, l; tsplit(v, h, l); hv[e] = h; lv[e] = l;
            }
            *(bf16x8*)&As[0][sl0 * 2][ml][0] = hv;
            *(bf16x8*)&As[1][sl0 * 2][ml][0] = lv;
            bf16x8 hv2 = {}, lv2 = {};
            { float v = sp[offt[8]] * wvt[8];
              short h, l; tsplit(v, h, l); hv2[0] = h; lv2[0] = l; }
            *(bf16x8*)&As[0][sl0 * 2 + 1][ml][0] = hv2;
            *(bf16x8*)&As[1][sl0 * 2 + 1][ml][0] = lv2;
        }
        __syncthreads();                           // As/Bs visible
        {
            const int kq = lane >> 4, r = lane & 15;
            #pragma unroll
            for (int kh = 0; kh < 2; kh++) {
                const int kgf = kh * 4 + kq;
                bf16x8 ah[4], al[4];
                #pragma unroll
                for (int i = 0; i < 4; i++) {
                    ah[i] = *(const bf16x8*)&As[0][kgf][wm + i * 16 + r][0];
                    al[i] = *(const bf16x8*)&As[1][kgf][wm + i * 16 + r][0];
                }
                bf16x8 bh = *(const bf16x8*)&Bs[0][kgf][wn + r][0];
                bf16x8 bl = *(const bf16x8*)&Bs[1][kgf][wn + r][0];
                #pragma unroll
                for (int i = 0; i < 4; i++) {
                    acc[i] = __builtin_amdgcn_mfma_f32_16x16x32_bf16(ah[i], bh, acc[i], 0, 0, 0);
                    acc[i] = __builtin_amdgcn_mfma_f32_16x16x32_bf16(al[i], bh, acc[i], 0, 0, 0);
                    acc[i] = __builtin_amdgcn_mfma_f32_16x16x32_bf16(ah[i], bl, acc[i], 0, 0, 0);
                }
            }
        }
        rv0 = pv0; rv1 = pv1;
    }

    const int kq = lane >> 4, rr = lane & 15;
    #pragma unroll
    for (int i = 0; i < 4; i++) {
        #pragma unroll
        for (int r = 0; r < 4; r++) {
            const int gm = bm + wm + i * 16 + kq * 4 + r;
            const int gn = bn + wn + rr;
            float v = acc[i][r];
            float* hp; int Hq, lr;
            if (gm < M1) { hp = outF; Hq = H0; lr = gm; }
            else         { hp = outF2; Hq = H1; lr = gm - M1; }
            int PL = Hq * Hq;
            int bq = lr / PL; int rem = lr - bq * PL;
            int yq = rem / Hq; int xq = rem - yq * Hq;
            hp[((size_t)bq * Cc + gn) * PL + yq * Hq + xq] = fmaxf(v + bias[gn], 0.f);
        }
    }
}

// =====================================================================
// mgemm4 (feat MODE 4 / scores MODE 5) — ROUND-19 EXACT: NO LDS,
// NO BARRIERS, BN=64, launch_bounds(256,3), reg ping-pong.
// GRID: dim3(nN, mt) -- n fastest (XCD B-strip pinning).
// =====================================================================
template<int MODE, int KD>
__global__ __launch_bounds__(TPB, 3)
void mgemm4(const short* __restrict__ AsH_, const short* __restrict__ AsL_,
            const short* __restrict__ Bh, const short* __restrict__ Bl,
            const float* __restrict__ bias,
            float* __restrict__ outF, short* __restrict__ outH,
            short* __restrict__ outL, int base)
{
    constexpr int NSTEP = KD / 32;          // 72 (feat) / 32 (scores), even
    const int tid = threadIdx.x;
    const int lane = tid & 63;
    const int wid = tid >> 6;
    const int wm = (wid >> 1) * 64, wn = (wid & 1) * 32;
    const int bm = blockIdx.y * 128, bn = blockIdx.x * 64;   // n fastest

    const size_t ablk0 = (size_t)(bm >> 7) * NSTEP * 4096;
    const size_t bblk0 = (size_t)(bn >> 7) * NSTEP * 4096;
    const int ai = wm >> 4;                  // 0 or 4
    const int bi = ((bn & 64) + wn) >> 4;    // 0..6
    const int lo8 = lane * 8;

    f32x4 acc[4][2];
    #pragma unroll
    for (int i = 0; i < 4; i++)
        #pragma unroll
        for (int j = 0; j < 2; j++)
            acc[i][j] = (f32x4){0.f, 0.f, 0.f, 0.f};

    bf16x8 Ah[2][4], Al[2][4], Bhf[2][2], Blf[2][2];

    auto LOAD = [&](int s, int t) {
        const size_t ab = ablk0 + (size_t)t * 4096;
        const size_t bb = bblk0 + (size_t)t * 4096;
        #pragma unroll
        for (int i = 0; i < 4; i++) {
            Ah[s][i] = *(const bf16x8*)(AsH_ + ab + (ai + i) * 512 + lo8);
            Al[s][i] = *(const bf16x8*)(AsL_ + ab + (ai + i) * 512 + lo8);
        }
        #pragma unroll
        for (int j = 0; j < 2; j++) {
            Bhf[s][j] = *(const bf16x8*)(Bh + bb + (bi + j) * 512 + lo8);
            Blf[s][j] = *(const bf16x8*)(Bl + bb + (bi + j) * 512 + lo8);
        }
    };
    auto MM = [&](int s) {
        #pragma unroll
        for (int i = 0; i < 4; i++)
            #pragma unroll
            for (int j = 0; j < 2; j++) {
                acc[i][j] = __builtin_amdgcn_mfma_f32_16x16x32_bf16(Ah[s][i], Bhf[s][j], acc[i][j], 0, 0, 0);
                acc[i][j] = __builtin_amdgcn_mfma_f32_16x16x32_bf16(Al[s][i], Bhf[s][j], acc[i][j], 0, 0, 0);
                acc[i][j] = __builtin_amdgcn_mfma_f32_16x16x32_bf16(Ah[s][i], Blf[s][j], acc[i][j], 0, 0, 0);
            }
    };

    LOAD(0, 0);
    for (int t = 0; t < NSTEP; t += 2) {
        LOAD(1, t + 1);                     // NSTEP even: t+1 < NSTEP always
        MM(0);
        if (t + 2 < NSTEP) LOAD(0, t + 2);
        MM(1);
    }

    const int kq = lane >> 4, rr = lane & 15;
    #pragma unroll
    for (int i = 0; i < 4; i++) {
        #pragma unroll
        for (int r = 0; r < 4; r++) {
            const int gm = bm + wm + i * 16 + kq * 4 + r;
            #pragma unroll
            for (int j = 0; j < 2; j++) {
                const int gn = bn + wn + j * 16 + rr;
                float v = acc[i][j][r];
                if constexpr (MODE == 4) {
                    float q = fmaxf(v + bias[gn], 0.f);
                    short h, l; tsplit(q, h, l);
                    size_t d = aidx(gm, gn, Ff);    // swizzled for scores-A
                    outH[d] = h;
                    outL[d] = l;
                } else {
                    if (gn < Oo) {
                        int g = base + gm;
                        int bq, pos;
                        if (g < N0) {
                            int lo = g & 63; bq = g >> 6;
                            pos = (lo & 7) * 8 + (lo >> 3);
                        } else {
                            int gg = g - N0; bq = gg / 324; int lo = gg - bq * 324;
                            int xq = lo / 18, yq = lo - xq * 18;
                            pos = L5 + yq * 18 + xq;
                        }
                        outF[((size_t)bq * Oo + gn) * LT + pos] = v + bias[gn];
                    }
                }
            }
        }
    }
}

// ===================== conv2 =====================
__global__ __launch_bounds__(TPB)
void conv2_k(const float* __restrict__ h0, const float* __restrict__ h1,
             const float* __restrict__ w1, float* __restrict__ c2)
{
    __shared__ float wl[6][KC];
    __shared__ float part[8][32][6];
    const int tid = threadIdx.x;
    for (int i = tid; i < 6 * KC; i += TPB) wl[i / KC][i - (i / KC) * KC] = w1[i];
    __syncthreads();
    const int row = blockIdx.x * 32 + (tid & 31);
    const int cig = tid >> 5;
    const float* hsrc; int H, S, loc;
    if (row < N0) { hsrc = h0; H = H0; S = S0; loc = row; }
    else          { hsrc = h1; H = H1; S = S1; loc = row - N0; }
    int SS = S * S;
    int b = loc / SS; int rem = loc - b * SS;
    int xq = rem / S; int yq = rem - xq * S;
    float acc[6] = {};
    for (int ci = cig * 32; ci < cig * 32 + 32; ci++) {
        const float* hp = hsrc + ((size_t)(b * Cc + ci) * H + yq) * H + xq;
        #pragma unroll
        for (int ky = 0; ky < 3; ky++)
            #pragma unroll
            for (int kx = 0; kx < 3; kx++) {
                float a = hp[ky * H + kx];
                int kk = ci * 9 + ky * 3 + kx;
                #pragma unroll
                for (int n = 0; n < 6; n++) acc[n] = fmaf(a, wl[n][kk], acc[n]);
            }
    }
    #pragma unroll
    for (int n = 0; n < 6; n++) part[cig][tid & 31][n] = acc[n];
    __syncthreads();
    if (cig == 0) {
        #pragma unroll
        for (int n = 0; n < 6; n++) {
            float s = 0.f;
            for (int g = 0; g < 8; g++) s += part[g][tid & 31][n];
            c2[(size_t)row * 6 + n] = s;
        }
    }
}

// ===================== theta / aux =====================
__global__ __launch_bounds__(TPB)
void theta_aux_k(const float* __restrict__ c2, const int* __restrict__ checkp,
                 float* __restrict__ td, float* __restrict__ gxy)
{
    int n = blockIdx.x * TPB + threadIdx.x;
    if (n >= NT_ALL) return;
    float omc = 1.0f - (float)checkp[0];
    const float I[6] = {1.f, 0.f, 0.f, 0.f, 1.f, 0.f};
    float th[6];
    #pragma unroll
    for (int i = 0; i < 6; i++) {
        float v = c2[(size_t)n * 6 + i] * omc + I[i];
        th[i] = v;
        td[(size_t)n * 6 + i] = I[i] - v;
    }
    int S, loc;
    if (n < N0) { S = S0; loc = n; } else { S = S1; loc = n - N0; }
    int SS = S * S;
    int rem = loc % SS;
    int xx = rem / S, yy = rem % S;
    #pragma unroll
    for (int ky = 0; ky < 3; ky++)
        #pragma unroll
        for (int kx = 0; kx < 3; kx++) {
            float bx = (float)(kx - 1), by = (float)(ky - 1);
            gxy[(size_t)n * 18 + ky * 3 + kx]     = th[0] * bx + th[1] * by + th[2] + 1.0f + (float)xx;
            gxy[(size_t)n * 18 + 9 + ky * 3 + kx] = th[3] * bx + th[4] * by + th[5] + 1.0f + (float)yy;
        }
}

// ==== fused softmax stats + likelihood + boxes (one kernel per batch) ====
__global__ __launch_bounds__(TPB)
void statsbox_k(const float* __restrict__ sc, const float* __restrict__ gxy,
                const int* __restrict__ imdp, float* __restrict__ lik,
                float* __restrict__ boxes, float* __restrict__ boxesNT,
                float* __restrict__ regpart)
{
    int b = blockIdx.x, tid = threadIdx.x;
    const float* p = sc + (size_t)b * Oo * LT;
    constexpr int PER = Oo * LT;
    __shared__ float red[TPB];
    __shared__ int redi[TPB];

    float m = -3.4e38f;
    for (int i = tid; i < PER; i += TPB) m = fmaxf(m, p[i]);
    red[tid] = m;
    for (int off = 128; off; off >>= 1) { __syncthreads(); if (tid < off) red[tid] = fmaxf(red[tid], red[tid + off]); }
    __syncthreads();
    m = red[0];
    __syncthreads();

    float so = 0.f;
    if (tid < Oo) {
        const float* q = p + (size_t)tid * LT;
        for (int i = 0; i < LT; i++) so += expf(q[i] - m);
    }
    red[tid] = so;
    for (int off = 128; off; off >>= 1) { __syncthreads(); if (tid < off) red[tid] += red[tid + off]; }
    __syncthreads();
    float smt = red[0];
    float mylik = (tid < Oo) ? so / smt : -3.4e38f;
    if (tid < Oo) lik[b * Oo + tid] = mylik;
    __syncthreads();

    red[tid] = mylik; redi[tid] = tid;
    for (int off = 128; off; off >>= 1) {
        __syncthreads();
        if (tid < off) {
            float v2 = red[tid + off]; int i2 = redi[tid + off];
            if (v2 > red[tid] || (v2 == red[tid] && i2 < redi[tid])) { red[tid] = v2; redi[tid] = i2; }
        }
    }
    __syncthreads();
    int pred = redi[0];
    __syncthreads();

    const float* pr = p + (size_t)pred * LT;
    float b5 = -3.4e38f; int i5 = 1 << 30;
    float b4 = -3.4e38f; int i4 = 1 << 30;
    for (int pos = tid; pos < LT; pos += TPB) {
        float s = pr[pos];
        if (pos < L5) { if (s > b5) { b5 = s; i5 = pos; } }
        else { int q = pos - L5; if (s > b4) { b4 = s; i4 = q; } }
    }
    red[tid] = b5; redi[tid] = i5;
    for (int off = 128; off; off >>= 1) {
        __syncthreads();
        if (tid < off) {
            float v2 = red[tid + off]; int i2 = redi[tid + off];
            if (v2 > red[tid] || (v2 == red[tid] && i2 < redi[tid])) { red[tid] = v2; redi[tid] = i2; }
        }
    }
    __syncthreads();
    float m5 = red[0]; int d5 = redi[0];
    __syncthreads();
    red[tid] = b4; redi[tid] = i4;
    for (int off = 128; off; off >>= 1) {
        __syncthreads();
        if (tid < off) {
            float v2 = red[tid + off]; int i2 = redi[tid + off];
            if (v2 > red[tid] || (v2 == red[tid] && i2 < redi[tid])) { red[tid] = v2; redi[tid] = i2; }
        }
    }
    __syncthreads();
    float m4 = red[0]; int d4 = redi[0];

    if (tid == 0) {
        float conf5 = expf(m5 - m) / smt;
        float conf4 = expf(m4 - m) / smt;
        float imd = (float)imdp[0];
        float lo = 0.f, hi = imd - 1.f;

        int xx5 = d5 % S0, yy5 = d5 / S0;
        int n5 = b * (S0 * S0) + xx5 * S0 + yy5;
        const float* g = gxy + (size_t)n5 * 18;
        float txm = 1e30f, txM = -1e30f, tym = 1e30f, tyM = -1e30f;
        for (int j = 0; j < 9; j++) {
            float tx = g[j] / 9.f, ty = g[9 + j] / 9.f;
            txm = fminf(txm, tx); txM = fmaxf(txM, tx);
            tym = fminf(tym, ty); tyM = fmaxf(tyM, ty);
        }
        float box5[5] = { clampf(txm * imd, lo, hi), clampf(tym * imd, lo, hi),
                          clampf(txM * imd, lo, hi), clampf(tyM * imd, lo, hi), conf5 };
        float nt5[5]  = { clampf((float)xx5 / 9.f * imd, lo, hi), clampf((float)yy5 / 9.f * imd, lo, hi),
                          clampf((float)(xx5 + 2) / 9.f * imd, lo, hi), clampf((float)(yy5 + 2) / 9.f * imd, lo, hi), conf5 };

        int xx4 = d4 % S1, yy4 = d4 / S1;
        int n4 = N0 + b * (S1 * S1) + xx4 * S1 + yy4;
        const float* g4 = gxy + (size_t)n4 * 18;
        float txm4 = 1e30f, txM4 = -1e30f, tym4 = 1e30f, tyM4 = -1e30f;
        for (int j = 0; j < 9; j++) {
            float tx = g4[j] / 19.f, ty = g4[9 + j] / 19.f;
            txm4 = fminf(txm4, tx); txM4 = fmaxf(txM4, tx);
            tym4 = fminf(tym4, ty); tyM4 = fmaxf(tyM4, ty);
        }
        float box4[5] = { clampf(txm4 * imd, lo, hi), clampf(tym4 * imd, lo, hi),
                          clampf(txM4 * imd, lo, hi), clampf(tyM4 * imd, lo, hi), conf4 };
        float nt4[5]  = { clampf((float)xx4 / 19.f * imd, lo, hi), clampf((float)yy4 / 19.f * imd, lo, hi),
                          clampf((float)(xx4 + 2) / 19.f * imd, lo, hi), clampf((float)(yy4 + 2) / 19.f * imd, lo, hi), conf4 };

        int mi = (conf4 > conf5) ? 1 : 0;
        for (int i = 0; i < 5; i++) {
            boxes[b * 5 + i]   = mi ? box4[i] : box5[i];
            boxesNT[b * 5 + i] = mi ? nt4[i] : nt5[i];
        }
        regpart[b] = fmaxf(conf4 - conf5, 0.f);
    }
}

__global__ void reg_k(const float* __restrict__ regpart, float* __restrict__ outreg)
{
    if (threadIdx.x == 0) {
        float s = 0.f;
        for (int b = 0; b < Bb; b++) s += regpart[b];
        outreg[0] = s;
    }
}

__global__ void sentinel_k(float* out, int n)
{
    int i = blockIdx.x * 256 + threadIdx.x;
    if (i < n) out[i] = 12345.0f;
}

extern "C" void kernel_launch(void* const* d_in, const int* in_sizes, int n_in,
                              void* d_out, int out_size, void* d_ws, size_t ws_size,
                              hipStream_t stream)
{
    const float* x0 = (const float*)d_in[0];
    const float* x1 = (const float*)d_in[1];
    const float* w0 = (const float*)d_in[2];
    const float* b0 = (const float*)d_in[3];
    const float* w1 = (const float*)d_in[4];
    const float* cw = (const float*)d_in[5];
    const float* cb = (const float*)d_in[6];
    const float* lw = (const float*)d_in[7];
    const float* lb = (const float*)d_in[8];
    const int* checkp = (const int*)d_in[9];
    const int* imdp   = (const int*)d_in[10];

    if (ws_size < B_END) {
        sentinel_k<<<dim3((out_size + 255) / 256), dim3(256), 0, stream>>>((float*)d_out, out_size);
        return;
    }

    char* wsb = (char*)d_ws;
    short* cwh = (short*)(wsb + B_CWH);
    short* cwl = (short*)(wsb + B_CWL);
    float* gxy = (float*)(wsb + B_GXY);
    short* lwh = (short*)(wsb + B_LWH);
    short* lwl = (short*)(wsb + B_LWL);
    float* sc  = (float*)(wsb + B_SC);
    short* xsH = (short*)(wsb + B_XSH);
    short* xsL = (short*)(wsb + B_XSL);
    short* fcH = (short*)(wsb + B_FCH);
    short* fcL = (short*)(wsb + B_FCL);
    float* rp  = (float*)(wsb + B_RP);
    short* w0h = (short*)(wsb + B_W0H);
    short* w0l = (short*)(wsb + B_W0L);
    float* h0  = (float*)(wsb + B_H0);
    float* h1  = (float*)(wsb + B_H1);
    float* c2  = (float*)(wsb + B_C2);

    float* out   = (float*)d_out;
    float* o_lik = out + O_LIK;
    float* o_box = out + O_BOX;
    float* o_nt  = out + O_NT;
    float* o_td  = out + O_TD;
    float* o_reg = out + O_REG;

    dim3 blk(TPB);

    // weight splits (cw/lw frag-swizzled; w0 conv1 layout)
    splitp_k  <<<dim3((Ff * 288 + TPB - 1) / TPB), blk, 0, stream>>>(cw, cwh, cwl, Ff);
    splitp16_k<<<dim3((int)((SZ_W0P + TPB - 1) / TPB)), blk, 0, stream>>>(w0, w0h, w0l, Cc);
    splitlw_k <<<dim3((int)((SZ_LWP + TPB - 1) / TPB)), blk, 0, stream>>>(lw, lwh, lwl);

    // merged conv1 (+bias, relu) -> h0/h1   [128x64 tile, 512 threads, BK=64]
    mgemm<KP><<<dim3(4, MCONV / 128), dim3(TPB2), 0, stream>>>(
        x0, x1, w0h, w0l, b0, h0, h1);

    // conv2 -> c2
    conv2_k<<<dim3(NT_ALL / 32), blk, 0, stream>>>(h0, h1, w1, c2);

    // theta, theta_diff, sampling coords
    theta_aux_k<<<dim3((NT_ALL + TPB - 1) / TPB), blk, 0, stream>>>(c2, checkp, o_td, gxy);

    // chunked: materialize xs (swizzled) -> feat GEMM -> scores GEMM
    const int bases[3] = {0, 4096, 8192};
    const int sizes[3] = {4096, 4096, 4224};
    for (int c = 0; c < 3; c++) {
        int basei = bases[c], rows = sizes[c];
        int mt = rows / 128;
        mat_k<<<dim3((rows * 288 + TPB - 1) / TPB), blk, 0, stream>>>(
            x0, x1, gxy, xsH, xsL, basei, rows);
        mgemm4<4, KC><<<dim3(16, mt), blk, 0, stream>>>(
            xsH, xsL, cwh, cwl, cb, nullptr, fcH, fcL, 0);
        mgemm4<5, Ff><<<dim3(4, mt), blk, 0, stream>>>(
            fcH, fcL, lwh, lwl, lb, sc, nullptr, nullptr, basei);
    }

    // fused softmax stats + likelihood + boxes, then reg
    statsbox_k<<<dim3(Bb), blk, 0, stream>>>(sc, gxy, imdp, o_lik, o_box, o_nt, rp);
    reg_k<<<dim3(1), dim3(64), 0, stream>>>(rp, o_reg);
}

// Round 22
// 855.088 us; speedup vs baseline: 1.0338x; 1.0015x over previous
//
#include <hip/hip_runtime.h>
#include <cmath>

#define TPB 256
#define TPB2 512

// ---- problem constants ----
constexpr int Bb = 32, Cc = 256, Ff = 1024, Oo = 201;
constexpr int H0 = 10, S0 = 8,  N0 = Bb * S0 * S0;   // 2048
constexpr int H1 = 20, S1 = 18, N1 = Bb * S1 * S1;   // 10368
constexpr int NT_ALL = N0 + N1;                      // 12416
constexpr int KC = Cc * 9;                           // 2304
constexpr int KP = Cc * 16;                          // 4096 (tap-padded conv1 K)
constexpr int L5 = S0 * S0, L4 = S1 * S1, LT = L5 + L4;  // 64, 324, 388
constexpr int CHMAX = 4224;                          // chunks: 4096,4096,4224
constexpr int M1 = Bb * H0 * H0;                     // 3200 (conv1 scale boundary)
constexpr int MCONV = M1 + Bb * H1 * H1;             // 16000

// ---- element counts ----
constexpr size_t SZ_CW  = (size_t)Ff * KC;      // 2,359,296
constexpr size_t SZ_W0P = (size_t)Cc * KP;      // 1,048,576
constexpr size_t SZ_LWP = (size_t)256 * Ff;     // 262,144 (padded to 256 rows)

// ---- workspace byte offsets ----
constexpr size_t B_CWH = 0;
constexpr size_t B_CWL = B_CWH + SZ_CW * 2;
constexpr size_t B_GXY = B_CWL + SZ_CW * 2;
constexpr size_t B_LWH = B_GXY + (size_t)NT_ALL * 18 * 4;
constexpr size_t B_LWL = B_LWH + SZ_LWP * 2;
constexpr size_t B_SC  = B_LWL + SZ_LWP * 2;
constexpr size_t B_XSH = B_SC + (size_t)Bb * Oo * LT * 4;
constexpr size_t B_XSL = B_XSH + (size_t)CHMAX * KC * 2;
constexpr size_t B_FCH = B_XSL + (size_t)CHMAX * KC * 2;
constexpr size_t B_FCL = B_FCH + (size_t)CHMAX * Ff * 2;
constexpr size_t B_RP  = B_FCL + (size_t)CHMAX * Ff * 2;   // ~77.6 MB
constexpr size_t B_END = B_RP + 256;
// aliases (disjoint lifetimes)
constexpr size_t B_W0H = B_XSH;
constexpr size_t B_W0L = B_XSH + SZ_W0P * 2;
constexpr size_t B_H0  = B_XSL;
constexpr size_t B_H1  = B_XSL + (size_t)Bb * Cc * H0 * H0 * 4;
constexpr size_t B_C2  = B_FCH;

// ---- output layout (floats) ----
constexpr size_t O_LIK = 0;
constexpr size_t O_BOX = O_LIK + Bb * Oo;
constexpr size_t O_NT  = O_BOX + Bb * 5;
constexpr size_t O_TD  = O_NT + Bb * 5;
constexpr size_t O_REG = O_TD + (size_t)NT_ALL * 6;

typedef __attribute__((ext_vector_type(8))) short bf16x8;
typedef __attribute__((ext_vector_type(4))) float f32x4;

__device__ __forceinline__ void tsplit(float v, short& h, short& l) {
    unsigned u = __builtin_bit_cast(unsigned, v);
    h = (short)(u >> 16);
    float hf = __builtin_bit_cast(float, u & 0xffff0000u);
    float r = v - hf;                       // exact
    l = (short)(__builtin_bit_cast(unsigned, r) >> 16);
}
__device__ __forceinline__ float clampf(float x, float lo, float hi) {
    return fminf(fmaxf(x, lo), hi);
}
__device__ __forceinline__ void gload16(const void* g, void* l) {
    __builtin_amdgcn_global_load_lds(
        (const __attribute__((address_space(1))) void*)g,
        (__attribute__((address_space(3))) void*)l, 16, 0, 0);
}
// fragment-swizzled element index: panel 128 rows x step 32 k -> 4096 block
__device__ __forceinline__ size_t aidx(int row, int k, int KD) {
    return ((size_t)(row >> 7) * (KD >> 5) + (k >> 5)) * 4096
         + (size_t)(((row & 127) >> 4) * 512 + ((k >> 3) & 3) * 128 + (row & 15) * 8 + (k & 7));
}

// ===================== weight split kernels =====================
// cw: k' = t*256 + c, frag-swizzled; thread = (row, tap, 8-ch group)
__global__ __launch_bounds__(TPB)
void splitp_k(const float* __restrict__ src, short* __restrict__ hi,
              short* __restrict__ lo, int nrows)
{
    int idx = blockIdx.x * TPB + threadIdx.x;
    if (idx >= nrows * 288) return;
    int row = idx / 288, r = idx - row * 288;
    int t = r >> 5, cg = r & 31;
    const float* sp = src + (size_t)row * KC + (size_t)cg * 8 * 9 + t;
    bf16x8 hv, lv;
    #pragma unroll
    for (int e = 0; e < 8; e++) {
        short h, l; tsplit(sp[e * 9], h, l);
        hv[e] = h; lv[e] = l;
    }
    size_t dst = aidx(row, t * 256 + cg * 8, KC);
    *(bf16x8*)&hi[dst] = hv;
    *(bf16x8*)&lo[dst] = lv;
}

__global__ __launch_bounds__(TPB)
void splitp16_k(const float* __restrict__ src, short* __restrict__ hi,
                short* __restrict__ lo, int nrows) // w0: k' = c*16 + t (conv1, row-major)
{
    int idx = blockIdx.x * TPB + threadIdx.x;
    if (idx >= nrows * KP) return;
    int row = idx >> 12, kq = idx & (KP - 1);
    int c = kq >> 4, t = kq & 15;
    float v = (t < 9) ? src[(size_t)row * KC + c * 9 + t] : 0.f;
    short h, l; tsplit(v, h, l);
    hi[idx] = h; lo[idx] = l;
}

__global__ __launch_bounds__(TPB)
void splitlw_k(const float* __restrict__ src, short* __restrict__ hi,
               short* __restrict__ lo)             // lw, 256-row pad, frag-swizzled
{
    int idx = blockIdx.x * TPB + threadIdx.x;
    if (idx >= (int)SZ_LWP) return;
    int row = idx >> 10, k = idx & 1023;
    float v = (row < Oo) ? src[idx] : 0.f;
    short h, l; tsplit(v, h, l);
    size_t dst = aidx(row, k, Ff);
    hi[dst] = h; lo[dst] = l;
}

// ===================== mat_k: materialize sampled im2col chunk (frag-swizzled) ====
__global__ __launch_bounds__(TPB)
void mat_k(const float* __restrict__ x0, const float* __restrict__ x1,
           const float* __restrict__ gxy, short* __restrict__ xsH,
           short* __restrict__ xsL, int base, int rows)
{
    int idx = blockIdx.x * TPB + threadIdx.x;
    if (idx >= rows * 288) return;
    int mloc = idx / 288, r = idx - mloc * 288;
    int j = r >> 5, cg = r & 31;
    int m = base + mloc;
    const float* xp; int H, loc, SS;
    if (m < N0) { xp = x0; H = H0; loc = m; SS = 64; }
    else        { xp = x1; H = H1; loc = m - N0; SS = 324; }
    int b = loc / SS;
    float gx = gxy[(size_t)m * 18 + j];
    float gy = gxy[(size_t)m * 18 + 9 + j];
    float xf = floorf(gx), yf = floorf(gy);
    float wx = gx - xf, wy = gy - yf;
    int ix = (int)xf, iy = (int)yf;
    int cx0 = min(max(ix, 0), H - 1), cy0 = min(max(iy, 0), H - 1);
    bool vx0 = (ix >= 0 && ix < H), vx1 = (ix >= -1 && ix < H - 1);
    bool vy0 = (iy >= 0 && iy < H), vy1 = (iy >= -1 && iy < H - 1);
    float wxL = vx0 ? (1.f - wx) : (vx1 ? wx : 0.f);
    float wxR = (vx0 && vx1) ? wx : 0.f;
    float wyT = vy0 ? (1.f - wy) : (vy1 ? wy : 0.f);
    float wyB = (vy0 && vy1) ? wy : 0.f;
    float wTL = wyT * wxL, wTR = wyT * wxR, wBL = wyB * wxL, wBR = wyB * wxR;
    int o   = cy0 * H + cx0;
    int oTR = (wTR != 0.f) ? o + 1     : o;
    int oBL = (wBL != 0.f) ? o + H     : o;
    int oBR = (wBR != 0.f) ? o + H + 1 : o;
    const float* cp = xp + ((size_t)b * Cc + cg * 8) * (H * H);
    bf16x8 hv, lv;
    #pragma unroll
    for (int e = 0; e < 8; e++) {
        float v = cp[o] * wTL + cp[oTR] * wTR + cp[oBL] * wBL + cp[oBR] * wBR;
        short h, l; tsplit(v, h, l); hv[e] = h; lv[e] = l;
        cp += H * H;
    }
    size_t dst = aidx(mloc, j * 256 + cg * 8, KC);   // e-contiguous
    *(bf16x8*)&xsH[dst] = hv;
    *(bf16x8*)&xsL[dst] = lv;
}

// =====================================================================
// mgemm (conv1) — ROUND-19 EXACT: 128x64 tile, 512 threads, BK=64.
// =====================================================================
template<int KD>
__global__ __launch_bounds__(TPB2, 4)
void mgemm(const float* __restrict__ x0s, const float* __restrict__ x1s,
           const short* __restrict__ Bh, const short* __restrict__ Bl,
           const float* __restrict__ bias,
           float* __restrict__ outF, float* __restrict__ outF2)
{
    __shared__ short As[2][8][128][8];   // 32 KB
    __shared__ short Bs[2][8][64][8];    // 16 KB
    __shared__ float slab[3200];         // 12.8 KB

    const int tid = threadIdx.x;          // 0..511
    const int lane = tid & 63;
    const int wid = tid >> 6;             // 0..7
    const int wm = (wid >> 2) * 64, wn = (wid & 3) * 16;
    const int ml = tid & 127;
    const int sl0 = tid >> 7;             // 0..3: channel within BK=64 phase
    const int bm = blockIdx.y * 128, bn = blockIdx.x * 64;

    f32x4 acc[4];
    #pragma unroll
    for (int i = 0; i < 4; i++) acc[i] = (f32x4){0.f, 0.f, 0.f, 0.f};

    const float* xsrc = nullptr;
    int Hh = 0, PLSZr = 0, UPPr = 0, bat0 = 0, batidx = 0, nu = 0;
    float wvt[9]; int offt[9];
    {
        int lbase;
        if (bm < M1) { xsrc = x0s; Hh = H0; lbase = bm; }
        else         { xsrc = x1s; Hh = H1; lbase = bm - M1; }
        PLSZr = Hh * Hh; UPPr = PLSZr >> 2;
        int mGl = lbase + ml;
        int bA = mGl / PLSZr; int rem = mGl - bA * PLSZr;
        int yA = rem / Hh, xA = rem - (rem / Hh) * Hh;
        bat0 = lbase / PLSZr;
        int nb = (lbase + 127) / PLSZr - bat0 + 1;
        batidx = bA - bat0;
        nu = nb * 4 * UPPr;               // <= 800 float4 units
        #pragma unroll
        for (int t = 0; t < 9; t++) {
            int ky = t / 3 - 1, kx = t - (t / 3) * 3 - 1;
            int yy = yA + ky, xx = xA + kx;
            bool ok = (yy >= 0 && yy < Hh && xx >= 0 && xx < Hh);
            offt[t] = ok ? (yy * Hh + xx) : 0;
            wvt[t] = ok ? 1.f : 0.f;
        }
    }

    float4 rv0 = {}, rv1 = {};
    float4 pv0 = {}, pv1 = {};
    auto issue_loads = [&](int kb, float4& a0, float4& a1) {
        const int c0 = kb >> 4;
        #pragma unroll
        for (int q = 0; q < 2; q++) {
            int i = tid + q * TPB2;
            if (i < nu) {
                int pl = i / UPPr, u = i - pl * UPPr;
                int bi = pl >> 2, ccq = pl & 3;
                float4 v = *(const float4*)(xsrc +
                    ((size_t)(bat0 + bi) * Cc + c0 + ccq) * PLSZr + u * 4);
                if (q == 0) a0 = v; else a1 = v;
            }
        }
    };
    auto write_slab = [&](const float4& a0, const float4& a1) {
        #pragma unroll
        for (int q = 0; q < 2; q++) {
            int i = tid + q * TPB2;
            if (i < nu)
                *(float4*)&slab[i * 4] = (q == 0) ? a0 : a1;
        }
    };

    issue_loads(0, rv0, rv1);

    for (int kb = 0; kb < KD; kb += 64) {
        write_slab(rv0, rv1);
        if (kb + 64 < KD) issue_loads(kb + 64, pv0, pv1);
        __syncthreads();                           // slab visible
        {
            int hilo = wid & 1, s0 = wid >> 1;
            const short* gB = (hilo ? Bl : Bh) + (size_t)(bn + lane) * KD + kb;
            gload16(gB + s0 * 8,       &Bs[hilo][s0][0][0]);
            gload16(gB + (s0 + 4) * 8, &Bs[hilo][s0 + 4][0][0]);
        }
        {
            const float* sp = &slab[(batidx * 4 + sl0) * PLSZr];
            bf16x8 hv, lv;
            #pragma unroll
            for (int e = 0; e < 8; e++) {
                float v = sp[offt[e]] * wvt[e];
                short h, l; tsplit(v, h, l); hv[e] = h; lv[e] = l;
            }
            *(bf16x8*)&As[0][sl0 * 2][ml][0] = hv;
            *(bf16x8*)&As[1][sl0 * 2][ml][0] = lv;
            bf16x8 hv2 = {}, lv2 = {};
            { float v = sp[offt[8]] * wvt[8];
              short h, l; tsplit(v, h, l); hv2[0] = h; lv2[0] = l; }
            *(bf16x8*)&As[0][sl0 * 2 + 1][ml][0] = hv2;
            *(bf16x8*)&As[1][sl0 * 2 + 1][ml][0] = lv2;
        }
        __syncthreads();                           // As/Bs visible
        {
            const int kq = lane >> 4, r = lane & 15;
            #pragma unroll
            for (int kh = 0; kh < 2; kh++) {
                const int kgf = kh * 4 + kq;
                bf16x8 ah[4], al[4];
                #pragma unroll
                for (int i = 0; i < 4; i++) {
                    ah[i] = *(const bf16x8*)&As[0][kgf][wm + i * 16 + r][0];
                    al[i] = *(const bf16x8*)&As[1][kgf][wm + i * 16 + r][0];
                }
                bf16x8 bh = *(const bf16x8*)&Bs[0][kgf][wn + r][0];
                bf16x8 bl = *(const bf16x8*)&Bs[1][kgf][wn + r][0];
                #pragma unroll
                for (int i = 0; i < 4; i++) {
                    acc[i] = __builtin_amdgcn_mfma_f32_16x16x32_bf16(ah[i], bh, acc[i], 0, 0, 0);
                    acc[i] = __builtin_amdgcn_mfma_f32_16x16x32_bf16(al[i], bh, acc[i], 0, 0, 0);
                    acc[i] = __builtin_amdgcn_mfma_f32_16x16x32_bf16(ah[i], bl, acc[i], 0, 0, 0);
                }
            }
        }
        rv0 = pv0; rv1 = pv1;
    }

    const int kq = lane >> 4, rr = lane & 15;
    #pragma unroll
    for (int i = 0; i < 4; i++) {
        #pragma unroll
        for (int r = 0; r < 4; r++) {
            const int gm = bm + wm + i * 16 + kq * 4 + r;
            const int gn = bn + wn + rr;
            float v = acc[i][r];
            float* hp; int Hq, lr;
            if (gm < M1) { hp = outF; Hq = H0; lr = gm; }
            else         { hp = outF2; Hq = H1; lr = gm - M1; }
            int PL = Hq * Hq;
            int bq = lr / PL; int rem = lr - bq * PL;
            int yq = rem / Hq; int xq = rem - yq * Hq;
            hp[((size_t)bq * Cc + gn) * PL + yq * Hq + xq] = fmaxf(v + bias[gn], 0.f);
        }
    }
}

// =====================================================================
// mgemm4 (feat MODE 4 / scores MODE 5): NO LDS, NO BARRIERS, reg
// ping-pong, lb3. BNT = block n-width: feat 64 (NJ=2), scores 32 (NJ=1,
// grid 8 x mt = 256 blocks -> full GPU coverage; B L2-resident).
// GRID: dim3(N/BNT, mt) -- n fastest (XCD B-strip pinning).
// =====================================================================
template<int MODE, int KD, int BNT>
__global__ __launch_bounds__(TPB, 3)
void mgemm4(const short* __restrict__ AsH_, const short* __restrict__ AsL_,
            const short* __restrict__ Bh, const short* __restrict__ Bl,
            const float* __restrict__ bias,
            float* __restrict__ outF, short* __restrict__ outH,
            short* __restrict__ outL, int base)
{
    constexpr int NSTEP = KD / 32;          // 72 (feat) / 32 (scores), even
    constexpr int NJ = BNT / 32;            // 2 (feat) / 1 (scores)
    const int tid = threadIdx.x;
    const int lane = tid & 63;
    const int wid = tid >> 6;
    const int wm = (wid >> 1) * 64, wn = (wid & 1) * (BNT / 2);
    const int bm = blockIdx.y * 128, bn = blockIdx.x * BNT;  // n fastest

    const size_t ablk0 = (size_t)(bm >> 7) * NSTEP * 4096;
    const size_t bblk0 = (size_t)(bn >> 7) * NSTEP * 4096;
    const int ai = wm >> 4;                  // 0 or 4
    const int bi = ((bn & 127) + wn) >> 4;   // 0..7
    const int lo8 = lane * 8;

    f32x4 acc[4][NJ];
    #pragma unroll
    for (int i = 0; i < 4; i++)
        #pragma unroll
        for (int j = 0; j < NJ; j++)
            acc[i][j] = (f32x4){0.f, 0.f, 0.f, 0.f};

    bf16x8 Ah[2][4], Al[2][4], Bhf[2][NJ], Blf[2][NJ];

    auto LOAD = [&](int s, int t) {
        const size_t ab = ablk0 + (size_t)t * 4096;
        const size_t bb = bblk0 + (size_t)t * 4096;
        #pragma unroll
        for (int i = 0; i < 4; i++) {
            Ah[s][i] = *(const bf16x8*)(AsH_ + ab + (ai + i) * 512 + lo8);
            Al[s][i] = *(const bf16x8*)(AsL_ + ab + (ai + i) * 512 + lo8);
        }
        #pragma unroll
        for (int j = 0; j < NJ; j++) {
            Bhf[s][j] = *(const bf16x8*)(Bh + bb + (bi + j) * 512 + lo8);
            Blf[s][j] = *(const bf16x8*)(Bl + bb + (bi + j) * 512 + lo8);
        }
    };
    auto MM = [&](int s) {
        #pragma unroll
        for (int i = 0; i < 4; i++)
            #pragma unroll
            for (int j = 0; j < NJ; j++) {
                acc[i][j] = __builtin_amdgcn_mfma_f32_16x16x32_bf16(Ah[s][i], Bhf[s][j], acc[i][j], 0, 0, 0);
                acc[i][j] = __builtin_amdgcn_mfma_f32_16x16x32_bf16(Al[s][i], Bhf[s][j], acc[i][j], 0, 0, 0);
                acc[i][j] = __builtin_amdgcn_mfma_f32_16x16x32_bf16(Ah[s][i], Blf[s][j], acc[i][j], 0, 0, 0);
            }
    };

    LOAD(0, 0);
    for (int t = 0; t < NSTEP; t += 2) {
        LOAD(1, t + 1);                     // NSTEP even: t+1 < NSTEP always
        MM(0);
        if (t + 2 < NSTEP) LOAD(0, t + 2);
        MM(1);
    }

    const int kq = lane >> 4, rr = lane & 15;
    #pragma unroll
    for (int i = 0; i < 4; i++) {
        #pragma unroll
        for (int r = 0; r < 4; r++) {
            const int gm = bm + wm + i * 16 + kq * 4 + r;
            #pragma unroll
            for (int j = 0; j < NJ; j++) {
                const int gn = bn + wn + j * 16 + rr;
                float v = acc[i][j][r];
                if constexpr (MODE == 4) {
                    float q = fmaxf(v + bias[gn], 0.f);
                    short h, l; tsplit(q, h, l);
                    size_t d = aidx(gm, gn, Ff);    // swizzled for scores-A
                    outH[d] = h;
                    outL[d] = l;
                } else {
                    if (gn < Oo) {
                        int g = base + gm;
                        int bq, pos;
                        if (g < N0) {
                            int lo = g & 63; bq = g >> 6;
                            pos = (lo & 7) * 8 + (lo >> 3);
                        } else {
                            int gg = g - N0; bq = gg / 324; int lo = gg - bq * 324;
                            int xq = lo / 18, yq = lo - xq * 18;
                            pos = L5 + yq * 18 + xq;
                        }
                        outF[((size_t)bq * Oo + gn) * LT + pos] = v + bias[gn];
                    }
                }
            }
        }
    }
}

// ===================== conv2 =====================
__global__ __launch_bounds__(TPB)
void conv2_k(const float* __restrict__ h0, const float* __restrict__ h1,
             const float* __restrict__ w1, float* __restrict__ c2)
{
    __shared__ float wl[6][KC];
    __shared__ float part[8][32][6];
    const int tid = threadIdx.x;
    for (int i = tid; i < 6 * KC; i += TPB) wl[i / KC][i - (i / KC) * KC] = w1[i];
    __syncthreads();
    const int row = blockIdx.x * 32 + (tid & 31);
    const int cig = tid >> 5;
    const float* hsrc; int H, S, loc;
    if (row < N0) { hsrc = h0; H = H0; S = S0; loc = row; }
    else          { hsrc = h1; H = H1; S = S1; loc = row - N0; }
    int SS = S * S;
    int b = loc / SS; int rem = loc - b * SS;
    int xq = rem / S; int yq = rem - xq * S;
    float acc[6] = {};
    for (int ci = cig * 32; ci < cig * 32 + 32; ci++) {
        const float* hp = hsrc + ((size_t)(b * Cc + ci) * H + yq) * H + xq;
        #pragma unroll
        for (int ky = 0; ky < 3; ky++)
            #pragma unroll
            for (int kx = 0; kx < 3; kx++) {
                float a = hp[ky * H + kx];
                int kk = ci * 9 + ky * 3 + kx;
                #pragma unroll
                for (int n = 0; n < 6; n++) acc[n] = fmaf(a, wl[n][kk], acc[n]);
            }
    }
    #pragma unroll
    for (int n = 0; n < 6; n++) part[cig][tid & 31][n] = acc[n];
    __syncthreads();
    if (cig == 0) {
        #pragma unroll
        for (int n = 0; n < 6; n++) {
            float s = 0.f;
            for (int g = 0; g < 8; g++) s += part[g][tid & 31][n];
            c2[(size_t)row * 6 + n] = s;
        }
    }
}

// ===================== theta / aux =====================
__global__ __launch_bounds__(TPB)
void theta_aux_k(const float* __restrict__ c2, const int* __restrict__ checkp,
                 float* __restrict__ td, float* __restrict__ gxy)
{
    int n = blockIdx.x * TPB + threadIdx.x;
    if (n >= NT_ALL) return;
    float omc = 1.0f - (float)checkp[0];
    const float I[6] = {1.f, 0.f, 0.f, 0.f, 1.f, 0.f};
    float th[6];
    #pragma unroll
    for (int i = 0; i < 6; i++) {
        float v = c2[(size_t)n * 6 + i] * omc + I[i];
        th[i] = v;
        td[(size_t)n * 6 + i] = I[i] - v;
    }
    int S, loc;
    if (n < N0) { S = S0; loc = n; } else { S = S1; loc = n - N0; }
    int SS = S * S;
    int rem = loc % SS;
    int xx = rem / S, yy = rem % S;
    #pragma unroll
    for (int ky = 0; ky < 3; ky++)
        #pragma unroll
        for (int kx = 0; kx < 3; kx++) {
            float bx = (float)(kx - 1), by = (float)(ky - 1);
            gxy[(size_t)n * 18 + ky * 3 + kx]     = th[0] * bx + th[1] * by + th[2] + 1.0f + (float)xx;
            gxy[(size_t)n * 18 + 9 + ky * 3 + kx] = th[3] * bx + th[4] * by + th[5] + 1.0f + (float)yy;
        }
}

// ==== fused softmax stats + likelihood + boxes (one kernel per batch) ====
__global__ __launch_bounds__(TPB)
void statsbox_k(const float* __restrict__ sc, const float* __restrict__ gxy,
                const int* __restrict__ imdp, float* __restrict__ lik,
                float* __restrict__ boxes, float* __restrict__ boxesNT,
                float* __restrict__ regpart)
{
    int b = blockIdx.x, tid = threadIdx.x;
    const float* p = sc + (size_t)b * Oo * LT;
    constexpr int PER = Oo * LT;
    __shared__ float red[TPB];
    __shared__ int redi[TPB];

    float m = -3.4e38f;
    for (int i = tid; i < PER; i += TPB) m = fmaxf(m, p[i]);
    red[tid] = m;
    for (int off = 128; off; off >>= 1) { __syncthreads(); if (tid < off) red[tid] = fmaxf(red[tid], red[tid + off]); }
    __syncthreads();
    m = red[0];
    __syncthreads();

    float so = 0.f;
    if (tid < Oo) {
        const float* q = p + (size_t)tid * LT;
        for (int i = 0; i < LT; i++) so += expf(q[i] - m);
    }
    red[tid] = so;
    for (int off = 128; off; off >>= 1) { __syncthreads(); if (tid < off) red[tid] += red[tid + off]; }
    __syncthreads();
    float smt = red[0];
    float mylik = (tid < Oo) ? so / smt : -3.4e38f;
    if (tid < Oo) lik[b * Oo + tid] = mylik;
    __syncthreads();

    red[tid] = mylik; redi[tid] = tid;
    for (int off = 128; off; off >>= 1) {
        __syncthreads();
        if (tid < off) {
            float v2 = red[tid + off]; int i2 = redi[tid + off];
            if (v2 > red[tid] || (v2 == red[tid] && i2 < redi[tid])) { red[tid] = v2; redi[tid] = i2; }
        }
    }
    __syncthreads();
    int pred = redi[0];
    __syncthreads();

    const float* pr = p + (size_t)pred * LT;
    float b5 = -3.4e38f; int i5 = 1 << 30;
    float b4 = -3.4e38f; int i4 = 1 << 30;
    for (int pos = tid; pos < LT; pos += TPB) {
        float s = pr[pos];
        if (pos < L5) { if (s > b5) { b5 = s; i5 = pos; } }
        else { int q = pos - L5; if (s > b4) { b4 = s; i4 = q; } }
    }
    red[tid] = b5; redi[tid] = i5;
    for (int off = 128; off; off >>= 1) {
        __syncthreads();
        if (tid < off) {
            float v2 = red[tid + off]; int i2 = redi[tid + off];
            if (v2 > red[tid] || (v2 == red[tid] && i2 < redi[tid])) { red[tid] = v2; redi[tid] = i2; }
        }
    }
    __syncthreads();
    float m5 = red[0]; int d5 = redi[0];
    __syncthreads();
    red[tid] = b4; redi[tid] = i4;
    for (int off = 128; off; off >>= 1) {
        __syncthreads();
        if (tid < off) {
            float v2 = red[tid + off]; int i2 = redi[tid + off];
            if (v2 > red[tid] || (v2 == red[tid] && i2 < redi[tid])) { red[tid] = v2; redi[tid] = i2; }
        }
    }
    __syncthreads();
    float m4 = red[0]; int d4 = redi[0];

    if (tid == 0) {
        float conf5 = expf(m5 - m) / smt;
        float conf4 = expf(m4 - m) / smt;
        float imd = (float)imdp[0];
        float lo = 0.f, hi = imd - 1.f;

        int xx5 = d5 % S0, yy5 = d5 / S0;
        int n5 = b * (S0 * S0) + xx5 * S0 + yy5;
        const float* g = gxy + (size_t)n5 * 18;
        float txm = 1e30f, txM = -1e30f, tym = 1e30f, tyM = -1e30f;
        for (int j = 0; j < 9; j++) {
            float tx = g[j] / 9.f, ty = g[9 + j] / 9.f;
            txm = fminf(txm, tx); txM = fmaxf(txM, tx);
            tym = fminf(tym, ty); tyM = fmaxf(tyM, ty);
        }
        float box5[5] = { clampf(txm * imd, lo, hi), clampf(tym * imd, lo, hi),
                          clampf(txM * imd, lo, hi), clampf(tyM * imd, lo, hi), conf5 };
        float nt5[5]  = { clampf((float)xx5 / 9.f * imd, lo, hi), clampf((float)yy5 / 9.f * imd, lo, hi),
                          clampf((float)(xx5 + 2) / 9.f * imd, lo, hi), clampf((float)(yy5 + 2) / 9.f * imd, lo, hi), conf5 };

        int xx4 = d4 % S1, yy4 = d4 / S1;
        int n4 = N0 + b * (S1 * S1) + xx4 * S1 + yy4;
        const float* g4 = gxy + (size_t)n4 * 18;
        float txm4 = 1e30f, txM4 = -1e30f, tym4 = 1e30f, tyM4 = -1e30f;
        for (int j = 0; j < 9; j++) {
            float tx = g4[j] / 19.f, ty = g4[9 + j] / 19.f;
            txm4 = fminf(txm4, tx); txM4 = fmaxf(txM4, tx);
            tym4 = fminf(tym4, ty); tyM4 = fmaxf(tyM4, ty);
        }
        float box4[5] = { clampf(txm4 * imd, lo, hi), clampf(tym4 * imd, lo, hi),
                          clampf(txM4 * imd, lo, hi), clampf(tyM4 * imd, lo, hi), conf4 };
        float nt4[5]  = { clampf((float)xx4 / 19.f * imd, lo, hi), clampf((float)yy4 / 19.f * imd, lo, hi),
                          clampf((float)(xx4 + 2) / 19.f * imd, lo, hi), clampf((float)(yy4 + 2) / 19.f * imd, lo, hi), conf4 };

        int mi = (conf4 > conf5) ? 1 : 0;
        for (int i = 0; i < 5; i++) {
            boxes[b * 5 + i]   = mi ? box4[i] : box5[i];
            boxesNT[b * 5 + i] = mi ? nt4[i] : nt5[i];
        }
        regpart[b] = fmaxf(conf4 - conf5, 0.f);
    }
}

__global__ void reg_k(const float* __restrict__ regpart, float* __restrict__ outreg)
{
    if (threadIdx.x == 0) {
        float s = 0.f;
        for (int b = 0; b < Bb; b++) s += regpart[b];
        outreg[0] = s;
    }
}

__global__ void sentinel_k(float* out, int n)
{
    int i = blockIdx.x * 256 + threadIdx.x;
    if (i < n) out[i] = 12345.0f;
}

extern "C" void kernel_launch(void* const* d_in, const int* in_sizes, int n_in,
                              void* d_out, int out_size, void* d_ws, size_t ws_size,
                              hipStream_t stream)
{
    const float* x0 = (const float*)d_in[0];
    const float* x1 = (const float*)d_in[1];
    const float* w0 = (const float*)d_in[2];
    const float* b0 = (const float*)d_in[3];
    const float* w1 = (const float*)d_in[4];
    const float* cw = (const float*)d_in[5];
    const float* cb = (const float*)d_in[6];
    const float* lw = (const float*)d_in[7];
    const float* lb = (const float*)d_in[8];
    const int* checkp = (const int*)d_in[9];
    const int* imdp   = (const int*)d_in[10];

    if (ws_size < B_END) {
        sentinel_k<<<dim3((out_size + 255) / 256), dim3(256), 0, stream>>>((float*)d_out, out_size);
        return;
    }

    char* wsb = (char*)d_ws;
    short* cwh = (short*)(wsb + B_CWH);
    short* cwl = (short*)(wsb + B_CWL);
    float* gxy = (float*)(wsb + B_GXY);
    short* lwh = (short*)(wsb + B_LWH);
    short* lwl = (short*)(wsb + B_LWL);
    float* sc  = (float*)(wsb + B_SC);
    short* xsH = (short*)(wsb + B_XSH);
    short* xsL = (short*)(wsb + B_XSL);
    short* fcH = (short*)(wsb + B_FCH);
    short* fcL = (short*)(wsb + B_FCL);
    float* rp  = (float*)(wsb + B_RP);
    short* w0h = (short*)(wsb + B_W0H);
    short* w0l = (short*)(wsb + B_W0L);
    float* h0  = (float*)(wsb + B_H0);
    float* h1  = (float*)(wsb + B_H1);
    float* c2  = (float*)(wsb + B_C2);

    float* out   = (float*)d_out;
    float* o_lik = out + O_LIK;
    float* o_box = out + O_BOX;
    float* o_nt  = out + O_NT;
    float* o_td  = out + O_TD;
    float* o_reg = out + O_REG;

    dim3 blk(TPB);

    // weight splits (cw/lw frag-swizzled; w0 conv1 layout)
    splitp_k  <<<dim3((Ff * 288 + TPB - 1) / TPB), blk, 0, stream>>>(cw, cwh, cwl, Ff);
    splitp16_k<<<dim3((int)((SZ_W0P + TPB - 1) / TPB)), blk, 0, stream>>>(w0, w0h, w0l, Cc);
    splitlw_k <<<dim3((int)((SZ_LWP + TPB - 1) / TPB)), blk, 0, stream>>>(lw, lwh, lwl);

    // merged conv1 (+bias, relu) -> h0/h1   [128x64 tile, 512 threads, BK=64]
    mgemm<KP><<<dim3(4, MCONV / 128), dim3(TPB2), 0, stream>>>(
        x0, x1, w0h, w0l, b0, h0, h1);

    // conv2 -> c2
    conv2_k<<<dim3(NT_ALL / 32), blk, 0, stream>>>(h0, h1, w1, c2);

    // theta, theta_diff, sampling coords
    theta_aux_k<<<dim3((NT_ALL + TPB - 1) / TPB), blk, 0, stream>>>(c2, checkp, o_td, gxy);

    // chunked: materialize xs (swizzled) -> feat GEMM (BNT=64) -> scores
    // GEMM (BNT=32, 256 blocks = full GPU)
    const int bases[3] = {0, 4096, 8192};
    const int sizes[3] = {4096, 4096, 4224};
    for (int c = 0; c < 3; c++) {
        int basei = bases[c], rows = sizes[c];
        int mt = rows / 128;
        mat_k<<<dim3((rows * 288 + TPB - 1) / TPB), blk, 0, stream>>>(
            x0, x1, gxy, xsH, xsL, basei, rows);
        mgemm4<4, KC, 64><<<dim3(16, mt), blk, 0, stream>>>(
            xsH, xsL, cwh, cwl, cb, nullptr, fcH, fcL, 0);
        mgemm4<5, Ff, 32><<<dim3(8, mt), blk, 0, stream>>>(
            fcH, fcL, lwh, lwl, lb, sc, nullptr, nullptr, basei);
    }

    // fused softmax stats + likelihood + boxes, then reg
    statsbox_k<<<dim3(Bb), blk, 0, stream>>>(sc, gxy, imdp, o_lik, o_box, o_nt, rp);
    reg_k<<<dim3(1), dim3(64), 0, stream>>>(rp, o_reg);
}